// Round 3
// baseline (2858.763 us; speedup 1.0000x reference)
//
#include <hip/hip_runtime.h>
#include <float.h>
#include <math.h>

// Problem constants
#define B_ 16
#define N_ 4096
#define S_ 1024
#define K_ 32
#define CIN0 67              // 3 + 64
#define NBS (B_ * S_)        // 16384
#define NEWXYZ_FLOATS (B_ * S_ * 3)  // 49152
#define AST 68               // LDS activation row stride

// ---------------- helpers ----------------

__device__ __forceinline__ float sqdist3(float x, float y, float z,
                                         float cx, float cy, float cz) {
#pragma clang fp contract(off)
  float dx = x - cx, dy = y - cy, dz = z - cz;
  float s = dx * dx;
  s = s + dy * dy;
  s = s + dz * dz;
  return s;
}

__device__ __forceinline__ float knn_dist(float c2, float cx, float cy, float cz,
                                          float x, float y, float z) {
#pragma clang fp contract(off)
  float dot = cx * x; dot = dot + cy * y; dot = dot + cz * z;
  float x2 = x * x;   x2 = x2 + y * y;   x2 = x2 + z * z;
  float d = c2 - 2.0f * dot;
  d = d + x2;
  return d;
}

// ---------------- FPS: one block (512 thr) per batch ----------------
// 8 points/thread held in REGISTERS (32 VGPRs of arrays -> no spill/remat;
// round-2's 16/thread forced LDS rematerialization, VGPR=68 + bank conflicts).
// Coordinates loaded straight from global. LDS copy of xyz kept only for the
// (arbitrary-index) centroid fetch. One barrier/step, double-buffered wave
// candidates, redundant all-thread resolve. Bit-exact vs numpy: contract(off)
// distances, first-index argmax tie-breaking (ascending index everywhere).
__global__ __launch_bounds__(512) void fps_kernel(
    const float* __restrict__ xyz, float* __restrict__ newxyz) {
  const int b = blockIdx.x;
  const int t = threadIdx.x;
  __shared__ float sx[N_ * 3];
  __shared__ float rval[2][8];
  __shared__ int ridx[2][8];
  const float* xb = xyz + (size_t)b * N_ * 3;
  for (int i = t; i < N_ * 3; i += 512) sx[i] = xb[i];
  // preload this thread's 8 consecutive points into registers (from global)
  float px[8], py[8], pz[8], dist[8];
#pragma unroll
  for (int j = 0; j < 8; ++j) {
    const int p = t * 8 + j;
    px[j] = xb[p * 3 + 0];
    py[j] = xb[p * 3 + 1];
    pz[j] = xb[p * 3 + 2];
    dist[j] = 1e10f;
  }
  __syncthreads();
  int far = 0;
  for (int s = 0; s < S_; ++s) {
    const float cx = sx[far * 3 + 0];
    const float cy = sx[far * 3 + 1];
    const float cz = sx[far * 3 + 2];
    if (t == 0) {
      float* o = newxyz + ((size_t)b * S_ + s) * 3;
      o[0] = cx; o[1] = cy; o[2] = cz;
    }
    float best = -1.0f;
    int bi = 0;
#pragma unroll
    for (int j = 0; j < 8; ++j) {  // ascending global idx -> strict '>' keeps first
      const float dd = sqdist3(px[j], py[j], pz[j], cx, cy, cz);
      const float nd = fminf(dist[j], dd);
      dist[j] = nd;
      if (nd > best) { best = nd; bi = t * 8 + j; }
    }
    // wave argmax (tie -> smaller index)
#pragma unroll
    for (int off = 32; off >= 1; off >>= 1) {
      const float ov = __shfl_xor(best, off);
      const int oi = __shfl_xor(bi, off);
      if (ov > best || (ov == best && oi < bi)) { best = ov; bi = oi; }
    }
    const int par = s & 1;
    if ((t & 63) == 0) { rval[par][t >> 6] = best; ridx[par][t >> 6] = bi; }
    __syncthreads();
    // all threads resolve the 8 wave candidates redundantly
    float bv = rval[par][0];
    int bj = ridx[par][0];
#pragma unroll
    for (int w = 1; w < 8; ++w) {
      const float v = rval[par][w];
      const int iw = ridx[par][w];
      if (v > bv || (v == bv && iw < bj)) { bv = v; bj = iw; }
    }
    far = bj;
  }
}

// ---------------- KNN: one wave per query, 4 queries/block ----------------
__global__ __launch_bounds__(256, 2) void knn_kernel(
    const float* __restrict__ xyz, const float* __restrict__ newxyz,
    int* __restrict__ knn_idx) {
  const int bs0 = blockIdx.x * 4;
  const int b = bs0 >> 10;
  const int t = threadIdx.x;
  const int wave = t >> 6;
  const int lane = t & 63;
  __shared__ float sxx[N_];
  __shared__ float sxy[N_];
  __shared__ float sxz[N_];
  const float* xb = xyz + (size_t)b * N_ * 3;
  for (int p = t; p < N_; p += 256) {
    sxx[p] = xb[p * 3 + 0];
    sxy[p] = xb[p * 3 + 1];
    sxz[p] = xb[p * 3 + 2];
  }
  __syncthreads();
  const int bs = bs0 + wave;
  const float cx = newxyz[(size_t)bs * 3 + 0];
  const float cy = newxyz[(size_t)bs * 3 + 1];
  const float cz = newxyz[(size_t)bs * 3 + 2];
  float c2;
  {
#pragma clang fp contract(off)
    float s = cx * cx;
    s = s + cy * cy;
    s = s + cz * cz;
    c2 = s;
  }
  float d[64];
  float gval[8];
  int gidx[8];
#pragma unroll
  for (int g = 0; g < 8; ++g) {
    float gv = FLT_MAX;
    int gi = g * 8;
#pragma unroll
    for (int q = 0; q < 8; ++q) {
      const int j = g * 8 + q;
      const int p = j * 64 + lane;
      const float dd = knn_dist(c2, cx, cy, cz, sxx[p], sxy[p], sxz[p]);
      d[j] = dd;
      if (dd < gv) { gv = dd; gi = j; }
    }
    gval[g] = gv; gidx[g] = gi;
  }
  int* krow = knn_idx + (size_t)bs * K_;
  for (int it = 0; it < K_; ++it) {
    float best = gval[0];
    int bj = gidx[0];
#pragma unroll
    for (int g = 1; g < 8; ++g) {
      if (gval[g] < best || (gval[g] == best && gidx[g] < bj)) { best = gval[g]; bj = gidx[g]; }
    }
    int bidx = bj * 64 + lane;
#pragma unroll
    for (int off = 32; off >= 1; off >>= 1) {
      const float ov = __shfl_xor(best, off);
      const int oi = __shfl_xor(bidx, off);
      if (ov < best || (ov == best && oi < bidx)) { best = ov; bidx = oi; }
    }
    if (lane == 0) krow[it] = bidx;
    if (lane == (bidx & 63)) {
      const int jl = bidx >> 6;
      const int gg = jl >> 3;
      const int qq = jl & 7;
#pragma unroll
      for (int g = 0; g < 8; ++g) {
        if (g == gg) {
#pragma unroll
          for (int q = 0; q < 8; ++q) {
            d[g * 8 + q] = (q == qq) ? FLT_MAX : d[g * 8 + q];
          }
          float gv = FLT_MAX;
          int gi = g * 8;
#pragma unroll
          for (int q = 0; q < 8; ++q) {
            const int j = g * 8 + q;
            if (d[j] < gv) { gv = d[j]; gi = j; }
          }
          gval[g] = gv; gidx[g] = gi;
        }
      }
    }
  }
}

// ---------------- MLP pass building blocks ----------------

__device__ __forceinline__ void loadw(float* __restrict__ wbuf,
                                      const float* __restrict__ w, int n, int t) {
  for (int i = t; i < n; i += 256) wbuf[i] = w[i];
}

__device__ __forceinline__ void loadw_half(float* __restrict__ wbuf,
                                           const float* __restrict__ w2, int ofs, int t) {
  for (int i = t; i < 64 * 64; i += 256) {
    const int c = i >> 6, j = i & 63;
    wbuf[i] = w2[c * 128 + ofs + j];
  }
}

__device__ __forceinline__ void build_x0(float* __restrict__ act,
    const float* __restrict__ xyz, const float* __restrict__ points,
    const int* __restrict__ knn_idx, const float* __restrict__ newxyz,
    int bs, int t) {
  const int b = bs >> 10;
  const int* krow = knn_idx + (size_t)bs * K_;
  const float cx = newxyz[(size_t)bs * 3 + 0];
  const float cy = newxyz[(size_t)bs * 3 + 1];
  const float cz = newxyz[(size_t)bs * 3 + 2];
  for (int i = t; i < K_ * CIN0; i += 256) {
    const int k = i / CIN0;
    const int c = i - k * CIN0;
    const int p = krow[k];
    float v;
    if (c < 3) {
      v = xyz[((size_t)b * N_ + p) * 3 + c] - (c == 0 ? cx : (c == 1 ? cy : cz));
    } else {
      v = points[((size_t)b * N_ + p) * 64 + (c - 3)];
    }
    act[k * AST + c] = v;
  }
}

template <int CIN>
__device__ __forceinline__ void matmul64(const float* __restrict__ act,
    const float* __restrict__ wbuf, const float* __restrict__ bias,
    float* __restrict__ out, int t) {
  const int k = t >> 3;
  const int g = t & 7;
  float acc[8];
#pragma unroll
  for (int j = 0; j < 8; ++j) acc[j] = bias[g * 8 + j];
  for (int c = 0; c < CIN; ++c) {
    const float xv = act[k * AST + c];
#pragma unroll
    for (int j = 0; j < 8; ++j) acc[j] += xv * wbuf[c * 64 + g * 8 + j];
  }
#pragma unroll
  for (int j = 0; j < 8; ++j) out[k * AST + g * 8 + j] = acc[j];
}

__device__ __forceinline__ void norm_relu64(float* __restrict__ act,
    const float* __restrict__ scale, const float* __restrict__ shift, int t) {
  for (int i = t; i < K_ * 64; i += 256) {
    const int k = i >> 6, c = i & 63;
    const float v = act[k * AST + c] * scale[c] + shift[c];
    act[k * AST + c] = fmaxf(v, 0.0f);
  }
}

__device__ __forceinline__ void stats64(const float* __restrict__ out,
    float* __restrict__ psum, float* __restrict__ psq, int bs, int ofs, int t) {
  if (t < 64) {
    float s = 0.f, q = 0.f;
    for (int k = 0; k < K_; ++k) {
      const float v = out[k * AST + t];
      s += v; q += v * v;
    }
    psum[(size_t)bs * 128 + ofs + t] = s;
    psq[(size_t)bs * 128 + ofs + t] = q;
  }
}

__device__ __forceinline__ void minmax64(const float* __restrict__ out,
    float* __restrict__ maxraw, float* __restrict__ minbuf, int bs, int ofs, int t) {
  if (t >= 64 && t < 128) {
    const int ch = t - 64;
    float mx = -FLT_MAX, mn = FLT_MAX;
    for (int k = 0; k < K_; ++k) {
      const float v = out[k * AST + ch];
      mx = fmaxf(mx, v); mn = fminf(mn, v);
    }
    maxraw[(size_t)bs * 128 + ofs + ch] = mx;
    minbuf[(size_t)bs * 128 + ofs + ch] = mn;
  }
}

// ---------------- Pass A ----------------
__global__ __launch_bounds__(256) void passA_kernel(
    const float* __restrict__ xyz, const float* __restrict__ points,
    const float* __restrict__ newxyz, const int* __restrict__ knn_idx,
    const float* __restrict__ w0, const float* __restrict__ b0,
    float* __restrict__ psum, float* __restrict__ psq) {
  __shared__ float actA[K_ * AST];
  __shared__ float outB[K_ * AST];
  __shared__ float wbuf[CIN0 * 64];
  const int bs = blockIdx.x, t = threadIdx.x;
  build_x0(actA, xyz, points, knn_idx, newxyz, bs, t);
  loadw(wbuf, w0, CIN0 * 64, t);
  __syncthreads();
  matmul64<CIN0>(actA, wbuf, b0, outB, t);
  __syncthreads();
  stats64(outB, psum, psq, bs, 0, t);
}

// ---------------- Pass B ----------------
__global__ __launch_bounds__(256) void passB_kernel(
    const float* __restrict__ xyz, const float* __restrict__ points,
    const float* __restrict__ newxyz, const int* __restrict__ knn_idx,
    const float* __restrict__ w0, const float* __restrict__ b0,
    const float* __restrict__ w1, const float* __restrict__ b1,
    const float* __restrict__ scales, const float* __restrict__ shifts,
    float* __restrict__ psum, float* __restrict__ psq) {
  __shared__ float actA[K_ * AST];
  __shared__ float outB[K_ * AST];
  __shared__ float wbuf[CIN0 * 64];
  const int bs = blockIdx.x, t = threadIdx.x;
  build_x0(actA, xyz, points, knn_idx, newxyz, bs, t);
  loadw(wbuf, w0, CIN0 * 64, t);
  __syncthreads();
  matmul64<CIN0>(actA, wbuf, b0, outB, t);
  __syncthreads();
  norm_relu64(outB, scales, shifts, t);
  loadw(wbuf, w1, 64 * 64, t);
  __syncthreads();
  matmul64<64>(outB, wbuf, b1, actA, t);
  __syncthreads();
  stats64(actA, psum, psq, bs, 0, t);
}

// ---------------- Pass C ----------------
__global__ __launch_bounds__(256) void passC_kernel(
    const float* __restrict__ xyz, const float* __restrict__ points,
    const float* __restrict__ newxyz, const int* __restrict__ knn_idx,
    const float* __restrict__ w0, const float* __restrict__ b0,
    const float* __restrict__ w1, const float* __restrict__ b1,
    const float* __restrict__ w2, const float* __restrict__ b2,
    const float* __restrict__ scales, const float* __restrict__ shifts,
    float* __restrict__ psum, float* __restrict__ psq,
    float* __restrict__ maxraw, float* __restrict__ minbuf) {
  __shared__ float actA[K_ * AST];
  __shared__ float outB[K_ * AST];
  __shared__ float wbuf[CIN0 * 64];
  const int bs = blockIdx.x, t = threadIdx.x;
  build_x0(actA, xyz, points, knn_idx, newxyz, bs, t);
  loadw(wbuf, w0, CIN0 * 64, t);
  __syncthreads();
  matmul64<CIN0>(actA, wbuf, b0, outB, t);
  __syncthreads();
  norm_relu64(outB, scales, shifts, t);
  loadw(wbuf, w1, 64 * 64, t);
  __syncthreads();
  matmul64<64>(outB, wbuf, b1, actA, t);
  __syncthreads();
  norm_relu64(actA, scales + 128, shifts + 128, t);
  loadw_half(wbuf, w2, 0, t);
  __syncthreads();
  matmul64<64>(actA, wbuf, b2, outB, t);
  __syncthreads();
  stats64(outB, psum, psq, bs, 0, t);
  minmax64(outB, maxraw, minbuf, bs, 0, t);
  loadw_half(wbuf, w2, 64, t);
  __syncthreads();
  matmul64<64>(actA, wbuf, b2 + 64, outB, t);
  __syncthreads();
  stats64(outB, psum, psq, bs, 64, t);
  minmax64(outB, maxraw, minbuf, bs, 64, t);
}

// ---------------- BN finalize ----------------
__global__ __launch_bounds__(256) void finalize_kernel(
    const float* __restrict__ psum, const float* __restrict__ psq,
    const float* __restrict__ g, const float* __restrict__ be,
    float* __restrict__ scale, float* __restrict__ shift) {
  const int ch = blockIdx.x, t = threadIdx.x;
  __shared__ float ss[256];
  __shared__ float sq[256];
  float s = 0.f, q = 0.f;
  for (int p = t; p < NBS; p += 256) {
    s += psum[(size_t)p * 128 + ch];
    q += psq[(size_t)p * 128 + ch];
  }
  ss[t] = s; sq[t] = q;
  __syncthreads();
  for (int off = 128; off >= 1; off >>= 1) {
    if (t < off) { ss[t] += ss[t + off]; sq[t] += sq[t + off]; }
    __syncthreads();
  }
  if (t == 0) {
    const float invN = 1.0f / (float)(B_ * S_ * K_);
    const float mean = ss[0] * invN;
    const float var = sq[0] * invN - mean * mean;
    const float sc = g[ch] / sqrtf(var + 1e-5f);
    scale[ch] = sc;
    shift[ch] = be[ch] - mean * sc;
  }
}

// ---------------- Final ----------------
__global__ __launch_bounds__(256) void final_kernel(
    const float* __restrict__ minbuf, const float* __restrict__ scale,
    const float* __restrict__ shift, float* __restrict__ out) {
  const int i = blockIdx.x * 256 + threadIdx.x;  // < B*S*128
  const int ch = i & 127;
  const float sc = scale[ch], sh = shift[ch];
  const float mx = out[NEWXYZ_FLOATS + i];
  const float mn = minbuf[i];
  const float v = sc * (sc >= 0.f ? mx : mn) + sh;
  out[NEWXYZ_FLOATS + i] = fmaxf(v, 0.f);
}

// ---------------- host ----------------
extern "C" void kernel_launch(void* const* d_in, const int* in_sizes, int n_in,
                              void* d_out, int out_size, void* d_ws, size_t ws_size,
                              hipStream_t stream) {
  const float* xyz = (const float*)d_in[0];
  const float* points = (const float*)d_in[1];
  const float* w0 = (const float*)d_in[2];
  const float* b0 = (const float*)d_in[3];
  const float* g0 = (const float*)d_in[4];
  const float* be0 = (const float*)d_in[5];
  const float* w1 = (const float*)d_in[6];
  const float* b1 = (const float*)d_in[7];
  const float* g1 = (const float*)d_in[8];
  const float* be1 = (const float*)d_in[9];
  const float* w2 = (const float*)d_in[10];
  const float* b2 = (const float*)d_in[11];
  const float* g2 = (const float*)d_in[12];
  const float* be2 = (const float*)d_in[13];
  float* out = (float*)d_out;

  float* ws = (float*)d_ws;
  int* knn_idx = (int*)ws;                 // B*S*K ints
  float* psum = ws + 524288;
  float* psq = psum + (size_t)NBS * 128;
  float* scales = psq + (size_t)NBS * 128;
  float* shifts = scales + 384;
  float* minbuf = shifts + 384;
  float* newxyz = out;
  float* maxraw = out + NEWXYZ_FLOATS;

  fps_kernel<<<B_, 512, 0, stream>>>(xyz, newxyz);
  knn_kernel<<<NBS / 4, 256, 0, stream>>>(xyz, newxyz, knn_idx);
  passA_kernel<<<NBS, 256, 0, stream>>>(xyz, points, newxyz, knn_idx, w0, b0, psum, psq);
  finalize_kernel<<<64, 256, 0, stream>>>(psum, psq, g0, be0, scales, shifts);
  passB_kernel<<<NBS, 256, 0, stream>>>(xyz, points, newxyz, knn_idx, w0, b0, w1, b1,
                                        scales, shifts, psum, psq);
  finalize_kernel<<<64, 256, 0, stream>>>(psum, psq, g1, be1, scales + 128, shifts + 128);
  passC_kernel<<<NBS, 256, 0, stream>>>(xyz, points, newxyz, knn_idx, w0, b0, w1, b1, w2, b2,
                                        scales, shifts, psum, psq, maxraw, minbuf);
  finalize_kernel<<<128, 256, 0, stream>>>(psum, psq, g2, be2, scales + 256, shifts + 256);
  final_kernel<<<(B_ * S_ * 128) / 256, 256, 0, stream>>>(minbuf, scales + 256, shifts + 256, out);
}

// Round 4
// 2722.012 us; speedup vs baseline: 1.0502x; 1.0502x over previous
//
#include <hip/hip_runtime.h>
#include <float.h>
#include <math.h>

// Problem constants
#define B_ 16
#define N_ 4096
#define S_ 1024
#define K_ 32
#define CIN0 67              // 3 + 64
#define NBS (B_ * S_)        // 16384
#define NEWXYZ_FLOATS (B_ * S_ * 3)  // 49152
#define AST 68               // LDS activation row stride

// ---------------- helpers ----------------

__device__ __forceinline__ float sqdist3(float x, float y, float z,
                                         float cx, float cy, float cz) {
#pragma clang fp contract(off)
  float dx = x - cx, dy = y - cy, dz = z - cz;
  float s = dx * dx;
  s = s + dy * dy;
  s = s + dz * dz;
  return s;
}

__device__ __forceinline__ float knn_dist(float c2, float cx, float cy, float cz,
                                          float x, float y, float z) {
#pragma clang fp contract(off)
  float dot = cx * x; dot = dot + cy * y; dot = dot + cz * z;
  float x2 = x * x;   x2 = x2 + y * y;   x2 = x2 + z * z;
  float d = c2 - 2.0f * dot;
  d = d + x2;
  return d;
}

// ---- DPP cross-lane (gfx9 encodings: row_shr:N=0x110|N, row_bcast15=0x142, row_bcast31=0x143) ----
template <int CTRL>
__device__ __forceinline__ float dpp_f(float v, float oldv) {
  return __int_as_float(__builtin_amdgcn_update_dpp(
      __float_as_int(oldv), __float_as_int(v), CTRL, 0xF, 0xF, false));
}
template <int CTRL>
__device__ __forceinline__ int dpp_i(int v, int oldv) {
  return __builtin_amdgcn_update_dpp(oldv, v, CTRL, 0xF, 0xF, false);
}

// argmax combine with (val,idx,x,y,z) carry; invalid lanes see val=-1 (< any dist>=0)
template <int CTRL>
__device__ __forceinline__ void fps_combine(float& val, int& idx,
                                            float& x, float& y, float& z) {
  const float tv = dpp_f<CTRL>(val, -1.0f);
  const int ti = dpp_i<CTRL>(idx, 0x7fffffff);
  const float tx = dpp_f<CTRL>(x, 0.0f);
  const float ty = dpp_f<CTRL>(y, 0.0f);
  const float tz = dpp_f<CTRL>(z, 0.0f);
  const bool take = (tv > val) || (tv == val && ti < idx);
  val = take ? tv : val;
  idx = take ? ti : idx;
  x = take ? tx : x;
  y = take ? ty : y;
  z = take ? tz : z;
}

// ---------------- FPS: one block (256 thr = 4 waves) per batch ----------------
// 16 pts/thread in REGISTERS (launch_bounds(256,1) -> 256-VGPR budget, no spill).
// Winner coords carried through local scan + DPP wave reduce + resolve, so each
// step's new centroid lands in registers: no LDS xyz copy, no dependent
// centroid ds_read. One barrier/step, double-buffered candidate slots.
// Bit-exact vs numpy: contract(off) distances, first-index argmax tie-break
// (ascending index scan; associative min-idx combine).
__global__ __launch_bounds__(256, 1) void fps_kernel(
    const float* __restrict__ xyz, float* __restrict__ newxyz) {
  const int b = blockIdx.x;
  const int t = threadIdx.x;
  __shared__ float rec[2][4][8];  // [parity][wave][val,idxbits,x,y,z,pad..]
  const float* xb = xyz + (size_t)b * N_ * 3;
  // preload this thread's 16 consecutive points into registers (from global)
  float px[16], py[16], pz[16], dist[16];
#pragma unroll
  for (int j = 0; j < 16; ++j) {
    const int p = t * 16 + j;
    px[j] = xb[p * 3 + 0];
    py[j] = xb[p * 3 + 1];
    pz[j] = xb[p * 3 + 2];
    dist[j] = 1e10f;
  }
  // first centroid = point 0 (reference: farthest init = 0)
  float cx = xb[0], cy = xb[1], cz = xb[2];
  for (int s = 0; s < S_; ++s) {
    if (t == 0) {
      float* o = newxyz + ((size_t)b * S_ + s) * 3;
      o[0] = cx; o[1] = cy; o[2] = cz;
    }
    // local argmax over 16 pts with coord carry (ascending j -> first on tie)
    float best = -1.0f;
    int bi = 0;
    float bx = 0.f, by = 0.f, bz = 0.f;
#pragma unroll
    for (int j = 0; j < 16; ++j) {
      const float dd = sqdist3(px[j], py[j], pz[j], cx, cy, cz);
      const float nd = fminf(dist[j], dd);
      dist[j] = nd;
      const bool take = nd > best;
      best = take ? nd : best;
      bi = take ? (t * 16 + j) : bi;
      bx = take ? px[j] : bx;
      by = take ? py[j] : by;
      bz = take ? pz[j] : bz;
    }
    // DPP wave argmax (result complete in lane 63)
    fps_combine<0x111>(best, bi, bx, by, bz);  // row_shr:1
    fps_combine<0x112>(best, bi, bx, by, bz);  // row_shr:2
    fps_combine<0x114>(best, bi, bx, by, bz);  // row_shr:4
    fps_combine<0x118>(best, bi, bx, by, bz);  // row_shr:8
    fps_combine<0x142>(best, bi, bx, by, bz);  // row_bcast:15
    fps_combine<0x143>(best, bi, bx, by, bz);  // row_bcast:31
    const float wv = __int_as_float(__builtin_amdgcn_readlane(__float_as_int(best), 63));
    const int wi = __builtin_amdgcn_readlane(bi, 63);
    const float wx = __int_as_float(__builtin_amdgcn_readlane(__float_as_int(bx), 63));
    const float wy = __int_as_float(__builtin_amdgcn_readlane(__float_as_int(by), 63));
    const float wz = __int_as_float(__builtin_amdgcn_readlane(__float_as_int(bz), 63));
    const int par = s & 1;
    if ((t & 63) == 0) {
      float* r = rec[par][t >> 6];
      r[0] = wv; r[1] = __int_as_float(wi); r[2] = wx; r[3] = wy; r[4] = wz;
    }
    __syncthreads();
    // all threads resolve the 4 wave candidates redundantly (broadcast reads)
    float bv = rec[par][0][0];
    int bj = __float_as_int(rec[par][0][1]);
    cx = rec[par][0][2]; cy = rec[par][0][3]; cz = rec[par][0][4];
#pragma unroll
    for (int w = 1; w < 4; ++w) {
      const float v = rec[par][w][0];
      const int iw = __float_as_int(rec[par][w][1]);
      const bool take = (v > bv) || (v == bv && iw < bj);
      bv = take ? v : bv;
      bj = take ? iw : bj;
      cx = take ? rec[par][w][2] : cx;
      cy = take ? rec[par][w][3] : cy;
      cz = take ? rec[par][w][4] : cz;
    }
  }
}

// ---------------- KNN: one wave per query, 4 queries/block ----------------
__global__ __launch_bounds__(256, 2) void knn_kernel(
    const float* __restrict__ xyz, const float* __restrict__ newxyz,
    int* __restrict__ knn_idx) {
  const int bs0 = blockIdx.x * 4;
  const int b = bs0 >> 10;
  const int t = threadIdx.x;
  const int wave = t >> 6;
  const int lane = t & 63;
  __shared__ float sxx[N_];
  __shared__ float sxy[N_];
  __shared__ float sxz[N_];
  const float* xb = xyz + (size_t)b * N_ * 3;
  for (int p = t; p < N_; p += 256) {
    sxx[p] = xb[p * 3 + 0];
    sxy[p] = xb[p * 3 + 1];
    sxz[p] = xb[p * 3 + 2];
  }
  __syncthreads();
  const int bs = bs0 + wave;
  const float cx = newxyz[(size_t)bs * 3 + 0];
  const float cy = newxyz[(size_t)bs * 3 + 1];
  const float cz = newxyz[(size_t)bs * 3 + 2];
  float c2;
  {
#pragma clang fp contract(off)
    float s = cx * cx;
    s = s + cy * cy;
    s = s + cz * cz;
    c2 = s;
  }
  float d[64];
  float gval[8];
  int gidx[8];
#pragma unroll
  for (int g = 0; g < 8; ++g) {
    float gv = FLT_MAX;
    int gi = g * 8;
#pragma unroll
    for (int q = 0; q < 8; ++q) {
      const int j = g * 8 + q;
      const int p = j * 64 + lane;
      const float dd = knn_dist(c2, cx, cy, cz, sxx[p], sxy[p], sxz[p]);
      d[j] = dd;
      if (dd < gv) { gv = dd; gi = j; }
    }
    gval[g] = gv; gidx[g] = gi;
  }
  int* krow = knn_idx + (size_t)bs * K_;
  for (int it = 0; it < K_; ++it) {
    float best = gval[0];
    int bj = gidx[0];
#pragma unroll
    for (int g = 1; g < 8; ++g) {
      if (gval[g] < best || (gval[g] == best && gidx[g] < bj)) { best = gval[g]; bj = gidx[g]; }
    }
    int bidx = bj * 64 + lane;
#pragma unroll
    for (int off = 32; off >= 1; off >>= 1) {
      const float ov = __shfl_xor(best, off);
      const int oi = __shfl_xor(bidx, off);
      if (ov < best || (ov == best && oi < bidx)) { best = ov; bidx = oi; }
    }
    if (lane == 0) krow[it] = bidx;
    if (lane == (bidx & 63)) {
      const int jl = bidx >> 6;
      const int gg = jl >> 3;
      const int qq = jl & 7;
#pragma unroll
      for (int g = 0; g < 8; ++g) {
        if (g == gg) {
#pragma unroll
          for (int q = 0; q < 8; ++q) {
            d[g * 8 + q] = (q == qq) ? FLT_MAX : d[g * 8 + q];
          }
          float gv = FLT_MAX;
          int gi = g * 8;
#pragma unroll
          for (int q = 0; q < 8; ++q) {
            const int j = g * 8 + q;
            if (d[j] < gv) { gv = d[j]; gi = j; }
          }
          gval[g] = gv; gidx[g] = gi;
        }
      }
    }
  }
}

// ---------------- MLP pass building blocks ----------------

__device__ __forceinline__ void loadw(float* __restrict__ wbuf,
                                      const float* __restrict__ w, int n, int t) {
  for (int i = t; i < n; i += 256) wbuf[i] = w[i];
}

__device__ __forceinline__ void loadw_half(float* __restrict__ wbuf,
                                           const float* __restrict__ w2, int ofs, int t) {
  for (int i = t; i < 64 * 64; i += 256) {
    const int c = i >> 6, j = i & 63;
    wbuf[i] = w2[c * 128 + ofs + j];
  }
}

__device__ __forceinline__ void build_x0(float* __restrict__ act,
    const float* __restrict__ xyz, const float* __restrict__ points,
    const int* __restrict__ knn_idx, const float* __restrict__ newxyz,
    int bs, int t) {
  const int b = bs >> 10;
  const int* krow = knn_idx + (size_t)bs * K_;
  const float cx = newxyz[(size_t)bs * 3 + 0];
  const float cy = newxyz[(size_t)bs * 3 + 1];
  const float cz = newxyz[(size_t)bs * 3 + 2];
  for (int i = t; i < K_ * CIN0; i += 256) {
    const int k = i / CIN0;
    const int c = i - k * CIN0;
    const int p = krow[k];
    float v;
    if (c < 3) {
      v = xyz[((size_t)b * N_ + p) * 3 + c] - (c == 0 ? cx : (c == 1 ? cy : cz));
    } else {
      v = points[((size_t)b * N_ + p) * 64 + (c - 3)];
    }
    act[k * AST + c] = v;
  }
}

template <int CIN>
__device__ __forceinline__ void matmul64(const float* __restrict__ act,
    const float* __restrict__ wbuf, const float* __restrict__ bias,
    float* __restrict__ out, int t) {
  const int k = t >> 3;
  const int g = t & 7;
  float acc[8];
#pragma unroll
  for (int j = 0; j < 8; ++j) acc[j] = bias[g * 8 + j];
  for (int c = 0; c < CIN; ++c) {
    const float xv = act[k * AST + c];
#pragma unroll
    for (int j = 0; j < 8; ++j) acc[j] += xv * wbuf[c * 64 + g * 8 + j];
  }
#pragma unroll
  for (int j = 0; j < 8; ++j) out[k * AST + g * 8 + j] = acc[j];
}

__device__ __forceinline__ void norm_relu64(float* __restrict__ act,
    const float* __restrict__ scale, const float* __restrict__ shift, int t) {
  for (int i = t; i < K_ * 64; i += 256) {
    const int k = i >> 6, c = i & 63;
    const float v = act[k * AST + c] * scale[c] + shift[c];
    act[k * AST + c] = fmaxf(v, 0.0f);
  }
}

__device__ __forceinline__ void stats64(const float* __restrict__ out,
    float* __restrict__ psum, float* __restrict__ psq, int bs, int ofs, int t) {
  if (t < 64) {
    float s = 0.f, q = 0.f;
    for (int k = 0; k < K_; ++k) {
      const float v = out[k * AST + t];
      s += v; q += v * v;
    }
    psum[(size_t)bs * 128 + ofs + t] = s;
    psq[(size_t)bs * 128 + ofs + t] = q;
  }
}

__device__ __forceinline__ void minmax64(const float* __restrict__ out,
    float* __restrict__ maxraw, float* __restrict__ minbuf, int bs, int ofs, int t) {
  if (t >= 64 && t < 128) {
    const int ch = t - 64;
    float mx = -FLT_MAX, mn = FLT_MAX;
    for (int k = 0; k < K_; ++k) {
      const float v = out[k * AST + ch];
      mx = fmaxf(mx, v); mn = fminf(mn, v);
    }
    maxraw[(size_t)bs * 128 + ofs + ch] = mx;
    minbuf[(size_t)bs * 128 + ofs + ch] = mn;
  }
}

// ---------------- Pass A ----------------
__global__ __launch_bounds__(256) void passA_kernel(
    const float* __restrict__ xyz, const float* __restrict__ points,
    const float* __restrict__ newxyz, const int* __restrict__ knn_idx,
    const float* __restrict__ w0, const float* __restrict__ b0,
    float* __restrict__ psum, float* __restrict__ psq) {
  __shared__ float actA[K_ * AST];
  __shared__ float outB[K_ * AST];
  __shared__ float wbuf[CIN0 * 64];
  const int bs = blockIdx.x, t = threadIdx.x;
  build_x0(actA, xyz, points, knn_idx, newxyz, bs, t);
  loadw(wbuf, w0, CIN0 * 64, t);
  __syncthreads();
  matmul64<CIN0>(actA, wbuf, b0, outB, t);
  __syncthreads();
  stats64(outB, psum, psq, bs, 0, t);
}

// ---------------- Pass B ----------------
__global__ __launch_bounds__(256) void passB_kernel(
    const float* __restrict__ xyz, const float* __restrict__ points,
    const float* __restrict__ newxyz, const int* __restrict__ knn_idx,
    const float* __restrict__ w0, const float* __restrict__ b0,
    const float* __restrict__ w1, const float* __restrict__ b1,
    const float* __restrict__ scales, const float* __restrict__ shifts,
    float* __restrict__ psum, float* __restrict__ psq) {
  __shared__ float actA[K_ * AST];
  __shared__ float outB[K_ * AST];
  __shared__ float wbuf[CIN0 * 64];
  const int bs = blockIdx.x, t = threadIdx.x;
  build_x0(actA, xyz, points, knn_idx, newxyz, bs, t);
  loadw(wbuf, w0, CIN0 * 64, t);
  __syncthreads();
  matmul64<CIN0>(actA, wbuf, b0, outB, t);
  __syncthreads();
  norm_relu64(outB, scales, shifts, t);
  loadw(wbuf, w1, 64 * 64, t);
  __syncthreads();
  matmul64<64>(outB, wbuf, b1, actA, t);
  __syncthreads();
  stats64(actA, psum, psq, bs, 0, t);
}

// ---------------- Pass C ----------------
__global__ __launch_bounds__(256) void passC_kernel(
    const float* __restrict__ xyz, const float* __restrict__ points,
    const float* __restrict__ newxyz, const int* __restrict__ knn_idx,
    const float* __restrict__ w0, const float* __restrict__ b0,
    const float* __restrict__ w1, const float* __restrict__ b1,
    const float* __restrict__ w2, const float* __restrict__ b2,
    const float* __restrict__ scales, const float* __restrict__ shifts,
    float* __restrict__ psum, float* __restrict__ psq,
    float* __restrict__ maxraw, float* __restrict__ minbuf) {
  __shared__ float actA[K_ * AST];
  __shared__ float outB[K_ * AST];
  __shared__ float wbuf[CIN0 * 64];
  const int bs = blockIdx.x, t = threadIdx.x;
  build_x0(actA, xyz, points, knn_idx, newxyz, bs, t);
  loadw(wbuf, w0, CIN0 * 64, t);
  __syncthreads();
  matmul64<CIN0>(actA, wbuf, b0, outB, t);
  __syncthreads();
  norm_relu64(outB, scales, shifts, t);
  loadw(wbuf, w1, 64 * 64, t);
  __syncthreads();
  matmul64<64>(outB, wbuf, b1, actA, t);
  __syncthreads();
  norm_relu64(actA, scales + 128, shifts + 128, t);
  loadw_half(wbuf, w2, 0, t);
  __syncthreads();
  matmul64<64>(actA, wbuf, b2, outB, t);
  __syncthreads();
  stats64(outB, psum, psq, bs, 0, t);
  minmax64(outB, maxraw, minbuf, bs, 0, t);
  loadw_half(wbuf, w2, 64, t);
  __syncthreads();
  matmul64<64>(actA, wbuf, b2 + 64, outB, t);
  __syncthreads();
  stats64(outB, psum, psq, bs, 64, t);
  minmax64(outB, maxraw, minbuf, bs, 64, t);
}

// ---------------- BN finalize ----------------
__global__ __launch_bounds__(256) void finalize_kernel(
    const float* __restrict__ psum, const float* __restrict__ psq,
    const float* __restrict__ g, const float* __restrict__ be,
    float* __restrict__ scale, float* __restrict__ shift) {
  const int ch = blockIdx.x, t = threadIdx.x;
  __shared__ float ss[256];
  __shared__ float sq[256];
  float s = 0.f, q = 0.f;
  for (int p = t; p < NBS; p += 256) {
    s += psum[(size_t)p * 128 + ch];
    q += psq[(size_t)p * 128 + ch];
  }
  ss[t] = s; sq[t] = q;
  __syncthreads();
  for (int off = 128; off >= 1; off >>= 1) {
    if (t < off) { ss[t] += ss[t + off]; sq[t] += sq[t + off]; }
    __syncthreads();
  }
  if (t == 0) {
    const float invN = 1.0f / (float)(B_ * S_ * K_);
    const float mean = ss[0] * invN;
    const float var = sq[0] * invN - mean * mean;
    const float sc = g[ch] / sqrtf(var + 1e-5f);
    scale[ch] = sc;
    shift[ch] = be[ch] - mean * sc;
  }
}

// ---------------- Final ----------------
__global__ __launch_bounds__(256) void final_kernel(
    const float* __restrict__ minbuf, const float* __restrict__ scale,
    const float* __restrict__ shift, float* __restrict__ out) {
  const int i = blockIdx.x * 256 + threadIdx.x;  // < B*S*128
  const int ch = i & 127;
  const float sc = scale[ch], sh = shift[ch];
  const float mx = out[NEWXYZ_FLOATS + i];
  const float mn = minbuf[i];
  const float v = sc * (sc >= 0.f ? mx : mn) + sh;
  out[NEWXYZ_FLOATS + i] = fmaxf(v, 0.f);
}

// ---------------- host ----------------
extern "C" void kernel_launch(void* const* d_in, const int* in_sizes, int n_in,
                              void* d_out, int out_size, void* d_ws, size_t ws_size,
                              hipStream_t stream) {
  const float* xyz = (const float*)d_in[0];
  const float* points = (const float*)d_in[1];
  const float* w0 = (const float*)d_in[2];
  const float* b0 = (const float*)d_in[3];
  const float* g0 = (const float*)d_in[4];
  const float* be0 = (const float*)d_in[5];
  const float* w1 = (const float*)d_in[6];
  const float* b1 = (const float*)d_in[7];
  const float* g1 = (const float*)d_in[8];
  const float* be1 = (const float*)d_in[9];
  const float* w2 = (const float*)d_in[10];
  const float* b2 = (const float*)d_in[11];
  const float* g2 = (const float*)d_in[12];
  const float* be2 = (const float*)d_in[13];
  float* out = (float*)d_out;

  float* ws = (float*)d_ws;
  int* knn_idx = (int*)ws;                 // B*S*K ints
  float* psum = ws + 524288;
  float* psq = psum + (size_t)NBS * 128;
  float* scales = psq + (size_t)NBS * 128;
  float* shifts = scales + 384;
  float* minbuf = shifts + 384;
  float* newxyz = out;
  float* maxraw = out + NEWXYZ_FLOATS;

  fps_kernel<<<B_, 256, 0, stream>>>(xyz, newxyz);
  knn_kernel<<<NBS / 4, 256, 0, stream>>>(xyz, newxyz, knn_idx);
  passA_kernel<<<NBS, 256, 0, stream>>>(xyz, points, newxyz, knn_idx, w0, b0, psum, psq);
  finalize_kernel<<<64, 256, 0, stream>>>(psum, psq, g0, be0, scales, shifts);
  passB_kernel<<<NBS, 256, 0, stream>>>(xyz, points, newxyz, knn_idx, w0, b0, w1, b1,
                                        scales, shifts, psum, psq);
  finalize_kernel<<<64, 256, 0, stream>>>(psum, psq, g1, be1, scales + 128, shifts + 128);
  passC_kernel<<<NBS, 256, 0, stream>>>(xyz, points, newxyz, knn_idx, w0, b0, w1, b1, w2, b2,
                                        scales, shifts, psum, psq, maxraw, minbuf);
  finalize_kernel<<<128, 256, 0, stream>>>(psum, psq, g2, be2, scales + 256, shifts + 256);
  final_kernel<<<(B_ * S_ * 128) / 256, 256, 0, stream>>>(minbuf, scales + 256, shifts + 256, out);
}

// Round 5
// 2351.541 us; speedup vs baseline: 1.2157x; 1.1575x over previous
//
#include <hip/hip_runtime.h>
#include <float.h>
#include <math.h>

// Problem constants
#define B_ 16
#define N_ 4096
#define S_ 1024
#define K_ 32
#define CIN0 67              // 3 + 64
#define NBS (B_ * S_)        // 16384
#define NEWXYZ_FLOATS (B_ * S_ * 3)  // 49152
#define AST 68               // LDS activation row stride

// ---------------- helpers ----------------

__device__ __forceinline__ float sqdist3(float x, float y, float z,
                                         float cx, float cy, float cz) {
#pragma clang fp contract(off)
  float dx = x - cx, dy = y - cy, dz = z - cz;
  float s = dx * dx;
  s = s + dy * dy;
  s = s + dz * dz;
  return s;
}

__device__ __forceinline__ float knn_dist(float c2, float cx, float cy, float cz,
                                          float x, float y, float z) {
#pragma clang fp contract(off)
  float dot = cx * x; dot = dot + cy * y; dot = dot + cz * z;
  float x2 = x * x;   x2 = x2 + y * y;   x2 = x2 + z * z;
  float d = c2 - 2.0f * dot;
  d = d + x2;
  return d;
}

// ---- DPP cross-lane (gfx9: row_shr:N=0x110|N, row_bcast15=0x142, row_bcast31=0x143) ----
template <int CTRL>
__device__ __forceinline__ float dpp_f(float v, float oldv) {
  return __int_as_float(__builtin_amdgcn_update_dpp(
      __float_as_int(oldv), __float_as_int(v), CTRL, 0xF, 0xF, false));
}
template <int CTRL>
__device__ __forceinline__ int dpp_i(int v, int oldv) {
  return __builtin_amdgcn_update_dpp(oldv, v, CTRL, 0xF, 0xF, false);
}

template <int CTRL>
__device__ __forceinline__ void fps_combine(float& val, int& idx,
                                            float& x, float& y, float& z) {
  const float tv = dpp_f<CTRL>(val, -1.0f);
  const int ti = dpp_i<CTRL>(idx, 0x7fffffff);
  const float tx = dpp_f<CTRL>(x, 0.0f);
  const float ty = dpp_f<CTRL>(y, 0.0f);
  const float tz = dpp_f<CTRL>(z, 0.0f);
  const bool take = (tv > val) || (tv == val && ti < idx);
  val = take ? tv : val;
  idx = take ? ti : idx;
  x = take ? tx : x;
  y = take ? ty : y;
  z = take ? tz : z;
}

// ---------------- FPS: one block (256 thr = 4 waves) per batch ----------------
// 16 pts/thread in REGISTERS. Round-4 lesson: loop-invariant coord loads get
// REMATERIALIZED into the loop (VGPR=64 proved arrays weren't kept) -> pin
// every element with asm so the compiler cannot re-derive them from memory.
// Winner coords carried through local scan + DPP wave reduce + resolve ->
// next centroid lands in registers (no LDS xyz, no dependent centroid read).
// Bit-exact vs numpy: contract(off) distances, first-index argmax tie-break.
__global__ __launch_bounds__(256, 1) void fps_kernel(
    const float* __restrict__ xyz, float* __restrict__ newxyz) {
  const int b = blockIdx.x;
  const int t = threadIdx.x;
  __shared__ float rec[2][4][8];  // [parity][wave][val,idxbits,x,y,z,...]
  const float* xb = xyz + (size_t)b * N_ * 3;
  float px[16], py[16], pz[16], dist[16];
#pragma unroll
  for (int j = 0; j < 16; ++j) {
    const int p = t * 16 + j;
    px[j] = xb[p * 3 + 0];
    py[j] = xb[p * 3 + 1];
    pz[j] = xb[p * 3 + 2];
    dist[j] = 1e10f;
  }
  // Pin: make values opaque so they MUST live in VGPRs (no remat from global).
#pragma unroll
  for (int j = 0; j < 16; ++j) {
    asm volatile("" : "+v"(px[j]), "+v"(py[j]), "+v"(pz[j]));
  }
  float cx = xb[0], cy = xb[1], cz = xb[2];  // farthest init = point 0
  for (int s = 0; s < S_; ++s) {
    if (t == 0) {
      float* o = newxyz + ((size_t)b * S_ + s) * 3;
      o[0] = cx; o[1] = cy; o[2] = cz;
    }
    float best = -1.0f;
    int bi = 0;
    float bx = 0.f, by = 0.f, bz = 0.f;
#pragma unroll
    for (int j = 0; j < 16; ++j) {  // ascending global idx -> first on tie
      const float dd = sqdist3(px[j], py[j], pz[j], cx, cy, cz);
      const float nd = fminf(dist[j], dd);
      dist[j] = nd;
      const bool take = nd > best;
      best = take ? nd : best;
      bi = take ? (t * 16 + j) : bi;
      bx = take ? px[j] : bx;
      by = take ? py[j] : by;
      bz = take ? pz[j] : bz;
    }
    fps_combine<0x111>(best, bi, bx, by, bz);  // row_shr:1
    fps_combine<0x112>(best, bi, bx, by, bz);  // row_shr:2
    fps_combine<0x114>(best, bi, bx, by, bz);  // row_shr:4
    fps_combine<0x118>(best, bi, bx, by, bz);  // row_shr:8
    fps_combine<0x142>(best, bi, bx, by, bz);  // row_bcast:15
    fps_combine<0x143>(best, bi, bx, by, bz);  // row_bcast:31
    const float wv = __int_as_float(__builtin_amdgcn_readlane(__float_as_int(best), 63));
    const int wi = __builtin_amdgcn_readlane(bi, 63);
    const float wx = __int_as_float(__builtin_amdgcn_readlane(__float_as_int(bx), 63));
    const float wy = __int_as_float(__builtin_amdgcn_readlane(__float_as_int(by), 63));
    const float wz = __int_as_float(__builtin_amdgcn_readlane(__float_as_int(bz), 63));
    const int par = s & 1;
    if ((t & 63) == 0) {
      float* r = rec[par][t >> 6];
      r[0] = wv; r[1] = __int_as_float(wi); r[2] = wx; r[3] = wy; r[4] = wz;
    }
    __syncthreads();
    float bv = rec[par][0][0];
    int bj = __float_as_int(rec[par][0][1]);
    cx = rec[par][0][2]; cy = rec[par][0][3]; cz = rec[par][0][4];
#pragma unroll
    for (int w = 1; w < 4; ++w) {
      const float v = rec[par][w][0];
      const int iw = __float_as_int(rec[par][w][1]);
      const bool take = (v > bv) || (v == bv && iw < bj);
      bv = take ? v : bv;
      bj = take ? iw : bj;
      cx = take ? rec[par][w][2] : cx;
      cy = take ? rec[par][w][3] : cy;
      cz = take ? rec[par][w][4] : cz;
    }
  }
}

// ---------------- KNN: one wave per query, 4 queries/block ----------------
__global__ __launch_bounds__(256, 2) void knn_kernel(
    const float* __restrict__ xyz, const float* __restrict__ newxyz,
    int* __restrict__ knn_idx) {
  const int bs0 = blockIdx.x * 4;
  const int b = bs0 >> 10;
  const int t = threadIdx.x;
  const int wave = t >> 6;
  const int lane = t & 63;
  __shared__ float sxx[N_];
  __shared__ float sxy[N_];
  __shared__ float sxz[N_];
  const float* xb = xyz + (size_t)b * N_ * 3;
  for (int p = t; p < N_; p += 256) {
    sxx[p] = xb[p * 3 + 0];
    sxy[p] = xb[p * 3 + 1];
    sxz[p] = xb[p * 3 + 2];
  }
  __syncthreads();
  const int bs = bs0 + wave;
  const float cx = newxyz[(size_t)bs * 3 + 0];
  const float cy = newxyz[(size_t)bs * 3 + 1];
  const float cz = newxyz[(size_t)bs * 3 + 2];
  float c2;
  {
#pragma clang fp contract(off)
    float s = cx * cx;
    s = s + cy * cy;
    s = s + cz * cz;
    c2 = s;
  }
  float d[64];
  float gval[8];
  int gidx[8];
#pragma unroll
  for (int g = 0; g < 8; ++g) {
    float gv = FLT_MAX;
    int gi = g * 8;
#pragma unroll
    for (int q = 0; q < 8; ++q) {
      const int j = g * 8 + q;
      const int p = j * 64 + lane;
      const float dd = knn_dist(c2, cx, cy, cz, sxx[p], sxy[p], sxz[p]);
      d[j] = dd;
      if (dd < gv) { gv = dd; gi = j; }
    }
    gval[g] = gv; gidx[g] = gi;
  }
  int* krow = knn_idx + (size_t)bs * K_;
  for (int it = 0; it < K_; ++it) {
    float best = gval[0];
    int bj = gidx[0];
#pragma unroll
    for (int g = 1; g < 8; ++g) {
      if (gval[g] < best || (gval[g] == best && gidx[g] < bj)) { best = gval[g]; bj = gidx[g]; }
    }
    int bidx = bj * 64 + lane;
#pragma unroll
    for (int off = 32; off >= 1; off >>= 1) {
      const float ov = __shfl_xor(best, off);
      const int oi = __shfl_xor(bidx, off);
      if (ov < best || (ov == best && oi < bidx)) { best = ov; bidx = oi; }
    }
    if (lane == 0) krow[it] = bidx;
    if (lane == (bidx & 63)) {
      const int jl = bidx >> 6;
      const int gg = jl >> 3;
      const int qq = jl & 7;
#pragma unroll
      for (int g = 0; g < 8; ++g) {
        if (g == gg) {
#pragma unroll
          for (int q = 0; q < 8; ++q) {
            d[g * 8 + q] = (q == qq) ? FLT_MAX : d[g * 8 + q];
          }
          float gv = FLT_MAX;
          int gi = g * 8;
#pragma unroll
          for (int q = 0; q < 8; ++q) {
            const int j = g * 8 + q;
            if (d[j] < gv) { gv = d[j]; gi = j; }
          }
          gval[g] = gv; gidx[g] = gi;
        }
      }
    }
  }
}

// ---------------- MLP pass building blocks ----------------

__device__ __forceinline__ void loadw(float* __restrict__ wbuf,
                                      const float* __restrict__ w, int n, int t) {
  for (int i = t; i < n; i += 256) wbuf[i] = w[i];
}

__device__ __forceinline__ void loadw_half(float* __restrict__ wbuf,
                                           const float* __restrict__ w2, int ofs, int t) {
  for (int i = t; i < 64 * 64; i += 256) {
    const int c = i >> 6, j = i & 63;
    wbuf[i] = w2[c * 128 + ofs + j];
  }
}

__device__ __forceinline__ void build_x0(float* __restrict__ act,
    const float* __restrict__ xyz, const float* __restrict__ points,
    const int* __restrict__ knn_idx, const float* __restrict__ newxyz,
    int bs, int t) {
  const int b = bs >> 10;
  const int* krow = knn_idx + (size_t)bs * K_;
  const float cx = newxyz[(size_t)bs * 3 + 0];
  const float cy = newxyz[(size_t)bs * 3 + 1];
  const float cz = newxyz[(size_t)bs * 3 + 2];
  for (int i = t; i < K_ * CIN0; i += 256) {
    const int k = i / CIN0;
    const int c = i - k * CIN0;
    const int p = krow[k];
    float v;
    if (c < 3) {
      v = xyz[((size_t)b * N_ + p) * 3 + c] - (c == 0 ? cx : (c == 1 ? cy : cz));
    } else {
      v = points[((size_t)b * N_ + p) * 64 + (c - 3)];
    }
    act[k * AST + c] = v;
  }
}

template <int CIN>
__device__ __forceinline__ void matmul64(const float* __restrict__ act,
    const float* __restrict__ wbuf, const float* __restrict__ bias,
    float* __restrict__ out, int t) {
  const int k = t >> 3;
  const int g = t & 7;
  float acc[8];
#pragma unroll
  for (int j = 0; j < 8; ++j) acc[j] = bias[g * 8 + j];
  for (int c = 0; c < CIN; ++c) {
    const float xv = act[k * AST + c];
#pragma unroll
    for (int j = 0; j < 8; ++j) acc[j] += xv * wbuf[c * 64 + g * 8 + j];
  }
#pragma unroll
  for (int j = 0; j < 8; ++j) out[k * AST + g * 8 + j] = acc[j];
}

__device__ __forceinline__ void norm_relu64(float* __restrict__ act,
    const float* __restrict__ scale, const float* __restrict__ shift, int t) {
  for (int i = t; i < K_ * 64; i += 256) {
    const int k = i >> 6, c = i & 63;
    const float v = act[k * AST + c] * scale[c] + shift[c];
    act[k * AST + c] = fmaxf(v, 0.0f);
  }
}

__device__ __forceinline__ void stats64(const float* __restrict__ out,
    float* __restrict__ psum, float* __restrict__ psq, int bs, int ofs, int t) {
  if (t < 64) {
    float s = 0.f, q = 0.f;
    for (int k = 0; k < K_; ++k) {
      const float v = out[k * AST + t];
      s += v; q += v * v;
    }
    psum[(size_t)bs * 128 + ofs + t] = s;
    psq[(size_t)bs * 128 + ofs + t] = q;
  }
}

__device__ __forceinline__ void minmax64(const float* __restrict__ out,
    float* __restrict__ maxraw, float* __restrict__ minbuf, int bs, int ofs, int t) {
  if (t >= 64 && t < 128) {
    const int ch = t - 64;
    float mx = -FLT_MAX, mn = FLT_MAX;
    for (int k = 0; k < K_; ++k) {
      const float v = out[k * AST + ch];
      mx = fmaxf(mx, v); mn = fminf(mn, v);
    }
    maxraw[(size_t)bs * 128 + ofs + ch] = mx;
    minbuf[(size_t)bs * 128 + ofs + ch] = mn;
  }
}

// ======== FAST PATH (activations stored in ws): A stores z0, B z0->z1, C z1->out ========

__global__ __launch_bounds__(256) void passA_store_kernel(
    const float* __restrict__ xyz, const float* __restrict__ points,
    const float* __restrict__ newxyz, const int* __restrict__ knn_idx,
    const float* __restrict__ w0, const float* __restrict__ b0,
    float* __restrict__ psum, float* __restrict__ psq, float* __restrict__ zbuf) {
  __shared__ float actA[K_ * AST];
  __shared__ float outB[K_ * AST];
  __shared__ float wbuf[CIN0 * 64];
  const int bs = blockIdx.x, t = threadIdx.x;
  build_x0(actA, xyz, points, knn_idx, newxyz, bs, t);
  loadw(wbuf, w0, CIN0 * 64, t);
  __syncthreads();
  matmul64<CIN0>(actA, wbuf, b0, outB, t);
  __syncthreads();
  stats64(outB, psum, psq, bs, 0, t);
  // store raw z0 (bit-identical to what the recompute path would produce)
  float* zrow = zbuf + (size_t)bs * 2048;
  for (int i = t; i < 2048; i += 256) zrow[i] = outB[(i >> 6) * AST + (i & 63)];
}

__global__ __launch_bounds__(256) void passB_z_kernel(
    const float* __restrict__ w1, const float* __restrict__ b1,
    const float* __restrict__ scales, const float* __restrict__ shifts,
    float* __restrict__ psum, float* __restrict__ psq, float* __restrict__ zbuf) {
  __shared__ float actA[K_ * AST];
  __shared__ float outB[K_ * AST];
  __shared__ float wbuf[64 * 64];
  const int bs = blockIdx.x, t = threadIdx.x;
  float* zrow = zbuf + (size_t)bs * 2048;
  for (int i = t; i < 2048; i += 256) outB[(i >> 6) * AST + (i & 63)] = zrow[i];
  loadw(wbuf, w1, 64 * 64, t);
  __syncthreads();
  norm_relu64(outB, scales, shifts, t);
  __syncthreads();
  matmul64<64>(outB, wbuf, b1, actA, t);
  __syncthreads();
  stats64(actA, psum, psq, bs, 0, t);
  for (int i = t; i < 2048; i += 256) zrow[i] = actA[(i >> 6) * AST + (i & 63)];
}

__global__ __launch_bounds__(256) void passC_z_kernel(
    const float* __restrict__ w2, const float* __restrict__ b2,
    const float* __restrict__ scales1, const float* __restrict__ shifts1,
    float* __restrict__ psum, float* __restrict__ psq,
    float* __restrict__ maxraw, float* __restrict__ minbuf,
    const float* __restrict__ zbuf) {
  __shared__ float actA[K_ * AST];
  __shared__ float outB[K_ * AST];
  __shared__ float wbuf[64 * 64];
  const int bs = blockIdx.x, t = threadIdx.x;
  const float* zrow = zbuf + (size_t)bs * 2048;
  for (int i = t; i < 2048; i += 256) actA[(i >> 6) * AST + (i & 63)] = zrow[i];
  loadw_half(wbuf, w2, 0, t);
  __syncthreads();
  norm_relu64(actA, scales1, shifts1, t);
  __syncthreads();
  matmul64<64>(actA, wbuf, b2, outB, t);
  __syncthreads();
  stats64(outB, psum, psq, bs, 0, t);
  minmax64(outB, maxraw, minbuf, bs, 0, t);
  loadw_half(wbuf, w2, 64, t);
  __syncthreads();
  matmul64<64>(actA, wbuf, b2 + 64, outB, t);
  __syncthreads();
  stats64(outB, psum, psq, bs, 64, t);
  minmax64(outB, maxraw, minbuf, bs, 64, t);
}

// ======== FALLBACK PATH (recompute, as round 4) ========

__global__ __launch_bounds__(256) void passA_kernel(
    const float* __restrict__ xyz, const float* __restrict__ points,
    const float* __restrict__ newxyz, const int* __restrict__ knn_idx,
    const float* __restrict__ w0, const float* __restrict__ b0,
    float* __restrict__ psum, float* __restrict__ psq) {
  __shared__ float actA[K_ * AST];
  __shared__ float outB[K_ * AST];
  __shared__ float wbuf[CIN0 * 64];
  const int bs = blockIdx.x, t = threadIdx.x;
  build_x0(actA, xyz, points, knn_idx, newxyz, bs, t);
  loadw(wbuf, w0, CIN0 * 64, t);
  __syncthreads();
  matmul64<CIN0>(actA, wbuf, b0, outB, t);
  __syncthreads();
  stats64(outB, psum, psq, bs, 0, t);
}

__global__ __launch_bounds__(256) void passB_kernel(
    const float* __restrict__ xyz, const float* __restrict__ points,
    const float* __restrict__ newxyz, const int* __restrict__ knn_idx,
    const float* __restrict__ w0, const float* __restrict__ b0,
    const float* __restrict__ w1, const float* __restrict__ b1,
    const float* __restrict__ scales, const float* __restrict__ shifts,
    float* __restrict__ psum, float* __restrict__ psq) {
  __shared__ float actA[K_ * AST];
  __shared__ float outB[K_ * AST];
  __shared__ float wbuf[CIN0 * 64];
  const int bs = blockIdx.x, t = threadIdx.x;
  build_x0(actA, xyz, points, knn_idx, newxyz, bs, t);
  loadw(wbuf, w0, CIN0 * 64, t);
  __syncthreads();
  matmul64<CIN0>(actA, wbuf, b0, outB, t);
  __syncthreads();
  norm_relu64(outB, scales, shifts, t);
  loadw(wbuf, w1, 64 * 64, t);
  __syncthreads();
  matmul64<64>(outB, wbuf, b1, actA, t);
  __syncthreads();
  stats64(actA, psum, psq, bs, 0, t);
}

__global__ __launch_bounds__(256) void passC_kernel(
    const float* __restrict__ xyz, const float* __restrict__ points,
    const float* __restrict__ newxyz, const int* __restrict__ knn_idx,
    const float* __restrict__ w0, const float* __restrict__ b0,
    const float* __restrict__ w1, const float* __restrict__ b1,
    const float* __restrict__ w2, const float* __restrict__ b2,
    const float* __restrict__ scales, const float* __restrict__ shifts,
    float* __restrict__ psum, float* __restrict__ psq,
    float* __restrict__ maxraw, float* __restrict__ minbuf) {
  __shared__ float actA[K_ * AST];
  __shared__ float outB[K_ * AST];
  __shared__ float wbuf[CIN0 * 64];
  const int bs = blockIdx.x, t = threadIdx.x;
  build_x0(actA, xyz, points, knn_idx, newxyz, bs, t);
  loadw(wbuf, w0, CIN0 * 64, t);
  __syncthreads();
  matmul64<CIN0>(actA, wbuf, b0, outB, t);
  __syncthreads();
  norm_relu64(outB, scales, shifts, t);
  loadw(wbuf, w1, 64 * 64, t);
  __syncthreads();
  matmul64<64>(outB, wbuf, b1, actA, t);
  __syncthreads();
  norm_relu64(actA, scales + 128, shifts + 128, t);
  loadw_half(wbuf, w2, 0, t);
  __syncthreads();
  matmul64<64>(actA, wbuf, b2, outB, t);
  __syncthreads();
  stats64(outB, psum, psq, bs, 0, t);
  minmax64(outB, maxraw, minbuf, bs, 0, t);
  loadw_half(wbuf, w2, 64, t);
  __syncthreads();
  matmul64<64>(actA, wbuf, b2 + 64, outB, t);
  __syncthreads();
  stats64(outB, psum, psq, bs, 64, t);
  minmax64(outB, maxraw, minbuf, bs, 64, t);
}

// ---------------- BN finalize ----------------
__global__ __launch_bounds__(256) void finalize_kernel(
    const float* __restrict__ psum, const float* __restrict__ psq,
    const float* __restrict__ g, const float* __restrict__ be,
    float* __restrict__ scale, float* __restrict__ shift) {
  const int ch = blockIdx.x, t = threadIdx.x;
  __shared__ float ss[256];
  __shared__ float sq[256];
  float s = 0.f, q = 0.f;
  for (int p = t; p < NBS; p += 256) {
    s += psum[(size_t)p * 128 + ch];
    q += psq[(size_t)p * 128 + ch];
  }
  ss[t] = s; sq[t] = q;
  __syncthreads();
  for (int off = 128; off >= 1; off >>= 1) {
    if (t < off) { ss[t] += ss[t + off]; sq[t] += sq[t + off]; }
    __syncthreads();
  }
  if (t == 0) {
    const float invN = 1.0f / (float)(B_ * S_ * K_);
    const float mean = ss[0] * invN;
    const float var = sq[0] * invN - mean * mean;
    const float sc = g[ch] / sqrtf(var + 1e-5f);
    scale[ch] = sc;
    shift[ch] = be[ch] - mean * sc;
  }
}

// ---------------- Final ----------------
__global__ __launch_bounds__(256) void final_kernel(
    const float* __restrict__ minbuf, const float* __restrict__ scale,
    const float* __restrict__ shift, float* __restrict__ out) {
  const int i = blockIdx.x * 256 + threadIdx.x;  // < B*S*128
  const int ch = i & 127;
  const float sc = scale[ch], sh = shift[ch];
  const float mx = out[NEWXYZ_FLOATS + i];
  const float mn = minbuf[i];
  const float v = sc * (sc >= 0.f ? mx : mn) + sh;
  out[NEWXYZ_FLOATS + i] = fmaxf(v, 0.f);
}

// ---------------- host ----------------
extern "C" void kernel_launch(void* const* d_in, const int* in_sizes, int n_in,
                              void* d_out, int out_size, void* d_ws, size_t ws_size,
                              hipStream_t stream) {
  const float* xyz = (const float*)d_in[0];
  const float* points = (const float*)d_in[1];
  const float* w0 = (const float*)d_in[2];
  const float* b0 = (const float*)d_in[3];
  const float* g0 = (const float*)d_in[4];
  const float* be0 = (const float*)d_in[5];
  const float* w1 = (const float*)d_in[6];
  const float* b1 = (const float*)d_in[7];
  const float* g1 = (const float*)d_in[8];
  const float* be1 = (const float*)d_in[9];
  const float* w2 = (const float*)d_in[10];
  const float* b2 = (const float*)d_in[11];
  const float* g2 = (const float*)d_in[12];
  const float* be2 = (const float*)d_in[13];
  float* out = (float*)d_out;
  float* newxyz = out;
  float* maxraw = out + NEWXYZ_FLOATS;

  float* ws = (float*)d_ws;
  // fast-path layout: knn | zbuf(33.55M floats) | psum | psq | scales | shifts | minbuf
  const size_t NEED_FAST =
      (size_t)(524288 + 16384 * 2048 + 2 * NBS * 128 + 768 + NBS * 128) * 4;

  fps_kernel<<<B_, 256, 0, stream>>>(xyz, newxyz);

  if (ws_size >= NEED_FAST) {
    int* knn_idx = (int*)ws;
    float* zbuf = ws + 524288;
    float* psum = zbuf + (size_t)16384 * 2048;
    float* psq = psum + (size_t)NBS * 128;
    float* scales = psq + (size_t)NBS * 128;
    float* shifts = scales + 384;
    float* minbuf = shifts + 384;
    knn_kernel<<<NBS / 4, 256, 0, stream>>>(xyz, newxyz, knn_idx);
    passA_store_kernel<<<NBS, 256, 0, stream>>>(xyz, points, newxyz, knn_idx, w0, b0,
                                                psum, psq, zbuf);
    finalize_kernel<<<64, 256, 0, stream>>>(psum, psq, g0, be0, scales, shifts);
    passB_z_kernel<<<NBS, 256, 0, stream>>>(w1, b1, scales, shifts, psum, psq, zbuf);
    finalize_kernel<<<64, 256, 0, stream>>>(psum, psq, g1, be1, scales + 128, shifts + 128);
    passC_z_kernel<<<NBS, 256, 0, stream>>>(w2, b2, scales + 128, shifts + 128,
                                            psum, psq, maxraw, minbuf, zbuf);
    finalize_kernel<<<128, 256, 0, stream>>>(psum, psq, g2, be2, scales + 256, shifts + 256);
    final_kernel<<<(B_ * S_ * 128) / 256, 256, 0, stream>>>(minbuf, scales + 256,
                                                            shifts + 256, out);
  } else {
    int* knn_idx = (int*)ws;
    float* psum = ws + 524288;
    float* psq = psum + (size_t)NBS * 128;
    float* scales = psq + (size_t)NBS * 128;
    float* shifts = scales + 384;
    float* minbuf = shifts + 384;
    knn_kernel<<<NBS / 4, 256, 0, stream>>>(xyz, newxyz, knn_idx);
    passA_kernel<<<NBS, 256, 0, stream>>>(xyz, points, newxyz, knn_idx, w0, b0, psum, psq);
    finalize_kernel<<<64, 256, 0, stream>>>(psum, psq, g0, be0, scales, shifts);
    passB_kernel<<<NBS, 256, 0, stream>>>(xyz, points, newxyz, knn_idx, w0, b0, w1, b1,
                                          scales, shifts, psum, psq);
    finalize_kernel<<<64, 256, 0, stream>>>(psum, psq, g1, be1, scales + 128, shifts + 128);
    passC_kernel<<<NBS, 256, 0, stream>>>(xyz, points, newxyz, knn_idx, w0, b0, w1, b1, w2, b2,
                                          scales, shifts, psum, psq, maxraw, minbuf);
    finalize_kernel<<<128, 256, 0, stream>>>(psum, psq, g2, be2, scales + 256, shifts + 256);
    final_kernel<<<(B_ * S_ * 128) / 256, 256, 0, stream>>>(minbuf, scales + 256,
                                                            shifts + 256, out);
  }
}

// Round 6
// 2169.536 us; speedup vs baseline: 1.3177x; 1.0839x over previous
//
#include <hip/hip_runtime.h>
#include <float.h>
#include <math.h>

// Problem constants
#define B_ 16
#define N_ 4096
#define S_ 1024
#define K_ 32
#define CIN0 67              // 3 + 64
#define NBS (B_ * S_)        // 16384
#define NEWXYZ_FLOATS (B_ * S_ * 3)  // 49152
#define AST 68               // LDS activation row stride

// ---------------- helpers ----------------

__device__ __forceinline__ float sqdist3(float x, float y, float z,
                                         float cx, float cy, float cz) {
#pragma clang fp contract(off)
  float dx = x - cx, dy = y - cy, dz = z - cz;
  float s = dx * dx;
  s = s + dy * dy;
  s = s + dz * dz;
  return s;
}

__device__ __forceinline__ float knn_dist(float c2, float cx, float cy, float cz,
                                          float x, float y, float z) {
#pragma clang fp contract(off)
  float dot = cx * x; dot = dot + cy * y; dot = dot + cz * z;
  float x2 = x * x;   x2 = x2 + y * y;   x2 = x2 + z * z;
  float d = c2 - 2.0f * dot;
  d = d + x2;
  return d;
}

// ---- DPP cross-lane (gfx9: row_shr:N=0x110|N, row_bcast15=0x142, row_bcast31=0x143) ----
template <int CTRL>
__device__ __forceinline__ float dpp_f(float v, float oldv) {
  return __int_as_float(__builtin_amdgcn_update_dpp(
      __float_as_int(oldv), __float_as_int(v), CTRL, 0xF, 0xF, false));
}
template <int CTRL>
__device__ __forceinline__ int dpp_i(int v, int oldv) {
  return __builtin_amdgcn_update_dpp(oldv, v, CTRL, 0xF, 0xF, false);
}

// argmax combine on (val,idx) only; invalid lanes see val=-1 (< any dist>=0)
template <int CTRL>
__device__ __forceinline__ void fps_combine2(float& val, int& idx) {
  const float tv = dpp_f<CTRL>(val, -1.0f);
  const int ti = dpp_i<CTRL>(idx, 0x7fffffff);
  const bool take = (tv > val) || (tv == val && ti < idx);
  val = take ? tv : val;
  idx = take ? ti : idx;
}

// ---------------- FPS: one block (256 thr = 4 waves) per batch ----------------
// Rounds 2-5 lesson: per-iteration coord loads inside the scan expose their
// latency (~200cyc x 16) no matter where they live; the register-pinning
// fight with the allocator is unwinnable (VGPR=40 despite "+v" pins).
// Design FOR memory instead: coords live in LDS as float4 (conflict-free
// lane-consecutive ds_read_b128, 16 INDEPENDENT unrolled reads per step ->
// scheduler batches them, latency overlapped). dist[16] stays in registers
// (true loop-carried state, allocator keeps it). DPP reduce carries (val,idx)
// only; winner coords re-fetched via one broadcast sp[bj] read.
// Bit-exact vs numpy: contract(off) distances, first-index argmax tie-break.
__global__ __launch_bounds__(256, 1) void fps_kernel(
    const float* __restrict__ xyz, float* __restrict__ newxyz) {
  const int b = blockIdx.x;
  const int t = threadIdx.x;
  __shared__ float4 sp[N_];       // 64 KB coords (x,y,z,0)
  __shared__ float rec[2][4][2];  // [parity][wave][val, idxbits]
  const float* xb = xyz + (size_t)b * N_ * 3;
  for (int p = t; p < N_; p += 256) {
    sp[p] = make_float4(xb[p * 3 + 0], xb[p * 3 + 1], xb[p * 3 + 2], 0.0f);
  }
  float dist[16];
#pragma unroll
  for (int j = 0; j < 16; ++j) dist[j] = 1e10f;
  __syncthreads();
  // first centroid = point 0 (reference: farthest init = 0)
  float4 c0 = sp[0];
  float cx = c0.x, cy = c0.y, cz = c0.z;
  for (int s = 0; s < S_; ++s) {
    if (t == 0) {
      float* o = newxyz + ((size_t)b * S_ + s) * 3;
      o[0] = cx; o[1] = cy; o[2] = cz;
    }
    float best = -1.0f;
    int bi = 0;
#pragma unroll
    for (int j = 0; j < 16; ++j) {  // p = j*256+t ascending in j -> first on tie
      const float4 p = sp[j * 256 + t];
      const float dd = sqdist3(p.x, p.y, p.z, cx, cy, cz);
      const float nd = fminf(dist[j], dd);
      dist[j] = nd;
      const bool take = nd > best;
      best = take ? nd : best;
      bi = take ? (j * 256 + t) : bi;
    }
    // DPP wave argmax (result complete in lane 63)
    fps_combine2<0x111>(best, bi);  // row_shr:1
    fps_combine2<0x112>(best, bi);  // row_shr:2
    fps_combine2<0x114>(best, bi);  // row_shr:4
    fps_combine2<0x118>(best, bi);  // row_shr:8
    fps_combine2<0x142>(best, bi);  // row_bcast:15
    fps_combine2<0x143>(best, bi);  // row_bcast:31
    const float wv = __int_as_float(__builtin_amdgcn_readlane(__float_as_int(best), 63));
    const int wi = __builtin_amdgcn_readlane(bi, 63);
    const int par = s & 1;
    if ((t & 63) == 0) {
      rec[par][t >> 6][0] = wv;
      rec[par][t >> 6][1] = __int_as_float(wi);
    }
    __syncthreads();
    // all threads resolve the 4 wave candidates redundantly (broadcast reads)
    float bv = rec[par][0][0];
    int bj = __float_as_int(rec[par][0][1]);
#pragma unroll
    for (int w = 1; w < 4; ++w) {
      const float v = rec[par][w][0];
      const int iw = __float_as_int(rec[par][w][1]);
      const bool take = (v > bv) || (v == bv && iw < bj);
      bv = take ? v : bv;
      bj = take ? iw : bj;
    }
    const float4 c = sp[bj];  // broadcast read
    cx = c.x; cy = c.y; cz = c.z;
  }
}

// ---------------- KNN: one wave per query, 4 queries/block ----------------
__global__ __launch_bounds__(256, 2) void knn_kernel(
    const float* __restrict__ xyz, const float* __restrict__ newxyz,
    int* __restrict__ knn_idx) {
  const int bs0 = blockIdx.x * 4;
  const int b = bs0 >> 10;
  const int t = threadIdx.x;
  const int wave = t >> 6;
  const int lane = t & 63;
  __shared__ float sxx[N_];
  __shared__ float sxy[N_];
  __shared__ float sxz[N_];
  const float* xb = xyz + (size_t)b * N_ * 3;
  for (int p = t; p < N_; p += 256) {
    sxx[p] = xb[p * 3 + 0];
    sxy[p] = xb[p * 3 + 1];
    sxz[p] = xb[p * 3 + 2];
  }
  __syncthreads();
  const int bs = bs0 + wave;
  const float cx = newxyz[(size_t)bs * 3 + 0];
  const float cy = newxyz[(size_t)bs * 3 + 1];
  const float cz = newxyz[(size_t)bs * 3 + 2];
  float c2;
  {
#pragma clang fp contract(off)
    float s = cx * cx;
    s = s + cy * cy;
    s = s + cz * cz;
    c2 = s;
  }
  float d[64];
  float gval[8];
  int gidx[8];
#pragma unroll
  for (int g = 0; g < 8; ++g) {
    float gv = FLT_MAX;
    int gi = g * 8;
#pragma unroll
    for (int q = 0; q < 8; ++q) {
      const int j = g * 8 + q;
      const int p = j * 64 + lane;
      const float dd = knn_dist(c2, cx, cy, cz, sxx[p], sxy[p], sxz[p]);
      d[j] = dd;
      if (dd < gv) { gv = dd; gi = j; }
    }
    gval[g] = gv; gidx[g] = gi;
  }
  int* krow = knn_idx + (size_t)bs * K_;
  for (int it = 0; it < K_; ++it) {
    float best = gval[0];
    int bj = gidx[0];
#pragma unroll
    for (int g = 1; g < 8; ++g) {
      if (gval[g] < best || (gval[g] == best && gidx[g] < bj)) { best = gval[g]; bj = gidx[g]; }
    }
    int bidx = bj * 64 + lane;
#pragma unroll
    for (int off = 32; off >= 1; off >>= 1) {
      const float ov = __shfl_xor(best, off);
      const int oi = __shfl_xor(bidx, off);
      if (ov < best || (ov == best && oi < bidx)) { best = ov; bidx = oi; }
    }
    if (lane == 0) krow[it] = bidx;
    if (lane == (bidx & 63)) {
      const int jl = bidx >> 6;
      const int gg = jl >> 3;
      const int qq = jl & 7;
#pragma unroll
      for (int g = 0; g < 8; ++g) {
        if (g == gg) {
#pragma unroll
          for (int q = 0; q < 8; ++q) {
            d[g * 8 + q] = (q == qq) ? FLT_MAX : d[g * 8 + q];
          }
          float gv = FLT_MAX;
          int gi = g * 8;
#pragma unroll
          for (int q = 0; q < 8; ++q) {
            const int j = g * 8 + q;
            if (d[j] < gv) { gv = d[j]; gi = j; }
          }
          gval[g] = gv; gidx[g] = gi;
        }
      }
    }
  }
}

// ---------------- MLP pass building blocks ----------------

__device__ __forceinline__ void loadw(float* __restrict__ wbuf,
                                      const float* __restrict__ w, int n, int t) {
  for (int i = t; i < n; i += 256) wbuf[i] = w[i];
}

__device__ __forceinline__ void loadw_half(float* __restrict__ wbuf,
                                           const float* __restrict__ w2, int ofs, int t) {
  for (int i = t; i < 64 * 64; i += 256) {
    const int c = i >> 6, j = i & 63;
    wbuf[i] = w2[c * 128 + ofs + j];
  }
}

__device__ __forceinline__ void build_x0(float* __restrict__ act,
    const float* __restrict__ xyz, const float* __restrict__ points,
    const int* __restrict__ knn_idx, const float* __restrict__ newxyz,
    int bs, int t) {
  const int b = bs >> 10;
  const int* krow = knn_idx + (size_t)bs * K_;
  const float cx = newxyz[(size_t)bs * 3 + 0];
  const float cy = newxyz[(size_t)bs * 3 + 1];
  const float cz = newxyz[(size_t)bs * 3 + 2];
  for (int i = t; i < K_ * CIN0; i += 256) {
    const int k = i / CIN0;
    const int c = i - k * CIN0;
    const int p = krow[k];
    float v;
    if (c < 3) {
      v = xyz[((size_t)b * N_ + p) * 3 + c] - (c == 0 ? cx : (c == 1 ? cy : cz));
    } else {
      v = points[((size_t)b * N_ + p) * 64 + (c - 3)];
    }
    act[k * AST + c] = v;
  }
}

template <int CIN>
__device__ __forceinline__ void matmul64(const float* __restrict__ act,
    const float* __restrict__ wbuf, const float* __restrict__ bias,
    float* __restrict__ out, int t) {
  const int k = t >> 3;
  const int g = t & 7;
  float acc[8];
#pragma unroll
  for (int j = 0; j < 8; ++j) acc[j] = bias[g * 8 + j];
  for (int c = 0; c < CIN; ++c) {
    const float xv = act[k * AST + c];
#pragma unroll
    for (int j = 0; j < 8; ++j) acc[j] += xv * wbuf[c * 64 + g * 8 + j];
  }
#pragma unroll
  for (int j = 0; j < 8; ++j) out[k * AST + g * 8 + j] = acc[j];
}

__device__ __forceinline__ void norm_relu64(float* __restrict__ act,
    const float* __restrict__ scale, const float* __restrict__ shift, int t) {
  for (int i = t; i < K_ * 64; i += 256) {
    const int k = i >> 6, c = i & 63;
    const float v = act[k * AST + c] * scale[c] + shift[c];
    act[k * AST + c] = fmaxf(v, 0.0f);
  }
}

__device__ __forceinline__ void stats64(const float* __restrict__ out,
    float* __restrict__ psum, float* __restrict__ psq, int bs, int ofs, int t) {
  if (t < 64) {
    float s = 0.f, q = 0.f;
    for (int k = 0; k < K_; ++k) {
      const float v = out[k * AST + t];
      s += v; q += v * v;
    }
    psum[(size_t)bs * 128 + ofs + t] = s;
    psq[(size_t)bs * 128 + ofs + t] = q;
  }
}

__device__ __forceinline__ void minmax64(const float* __restrict__ out,
    float* __restrict__ maxraw, float* __restrict__ minbuf, int bs, int ofs, int t) {
  if (t >= 64 && t < 128) {
    const int ch = t - 64;
    float mx = -FLT_MAX, mn = FLT_MAX;
    for (int k = 0; k < K_; ++k) {
      const float v = out[k * AST + ch];
      mx = fmaxf(mx, v); mn = fminf(mn, v);
    }
    maxraw[(size_t)bs * 128 + ofs + ch] = mx;
    minbuf[(size_t)bs * 128 + ofs + ch] = mn;
  }
}

// ======== FAST PATH (activations stored in ws) ========

__global__ __launch_bounds__(256) void passA_store_kernel(
    const float* __restrict__ xyz, const float* __restrict__ points,
    const float* __restrict__ newxyz, const int* __restrict__ knn_idx,
    const float* __restrict__ w0, const float* __restrict__ b0,
    float* __restrict__ psum, float* __restrict__ psq, float* __restrict__ zbuf) {
  __shared__ float actA[K_ * AST];
  __shared__ float outB[K_ * AST];
  __shared__ float wbuf[CIN0 * 64];
  const int bs = blockIdx.x, t = threadIdx.x;
  build_x0(actA, xyz, points, knn_idx, newxyz, bs, t);
  loadw(wbuf, w0, CIN0 * 64, t);
  __syncthreads();
  matmul64<CIN0>(actA, wbuf, b0, outB, t);
  __syncthreads();
  stats64(outB, psum, psq, bs, 0, t);
  float* zrow = zbuf + (size_t)bs * 2048;
  for (int i = t; i < 2048; i += 256) zrow[i] = outB[(i >> 6) * AST + (i & 63)];
}

__global__ __launch_bounds__(256) void passB_z_kernel(
    const float* __restrict__ w1, const float* __restrict__ b1,
    const float* __restrict__ scales, const float* __restrict__ shifts,
    float* __restrict__ psum, float* __restrict__ psq, float* __restrict__ zbuf) {
  __shared__ float actA[K_ * AST];
  __shared__ float outB[K_ * AST];
  __shared__ float wbuf[64 * 64];
  const int bs = blockIdx.x, t = threadIdx.x;
  float* zrow = zbuf + (size_t)bs * 2048;
  for (int i = t; i < 2048; i += 256) outB[(i >> 6) * AST + (i & 63)] = zrow[i];
  loadw(wbuf, w1, 64 * 64, t);
  __syncthreads();
  norm_relu64(outB, scales, shifts, t);
  __syncthreads();
  matmul64<64>(outB, wbuf, b1, actA, t);
  __syncthreads();
  stats64(actA, psum, psq, bs, 0, t);
  for (int i = t; i < 2048; i += 256) zrow[i] = actA[(i >> 6) * AST + (i & 63)];
}

__global__ __launch_bounds__(256) void passC_z_kernel(
    const float* __restrict__ w2, const float* __restrict__ b2,
    const float* __restrict__ scales1, const float* __restrict__ shifts1,
    float* __restrict__ psum, float* __restrict__ psq,
    float* __restrict__ maxraw, float* __restrict__ minbuf,
    const float* __restrict__ zbuf) {
  __shared__ float actA[K_ * AST];
  __shared__ float outB[K_ * AST];
  __shared__ float wbuf[64 * 64];
  const int bs = blockIdx.x, t = threadIdx.x;
  const float* zrow = zbuf + (size_t)bs * 2048;
  for (int i = t; i < 2048; i += 256) actA[(i >> 6) * AST + (i & 63)] = zrow[i];
  loadw_half(wbuf, w2, 0, t);
  __syncthreads();
  norm_relu64(actA, scales1, shifts1, t);
  __syncthreads();
  matmul64<64>(actA, wbuf, b2, outB, t);
  __syncthreads();
  stats64(outB, psum, psq, bs, 0, t);
  minmax64(outB, maxraw, minbuf, bs, 0, t);
  loadw_half(wbuf, w2, 64, t);
  __syncthreads();
  matmul64<64>(actA, wbuf, b2 + 64, outB, t);
  __syncthreads();
  stats64(outB, psum, psq, bs, 64, t);
  minmax64(outB, maxraw, minbuf, bs, 64, t);
}

// ======== FALLBACK PATH (recompute) ========

__global__ __launch_bounds__(256) void passA_kernel(
    const float* __restrict__ xyz, const float* __restrict__ points,
    const float* __restrict__ newxyz, const int* __restrict__ knn_idx,
    const float* __restrict__ w0, const float* __restrict__ b0,
    float* __restrict__ psum, float* __restrict__ psq) {
  __shared__ float actA[K_ * AST];
  __shared__ float outB[K_ * AST];
  __shared__ float wbuf[CIN0 * 64];
  const int bs = blockIdx.x, t = threadIdx.x;
  build_x0(actA, xyz, points, knn_idx, newxyz, bs, t);
  loadw(wbuf, w0, CIN0 * 64, t);
  __syncthreads();
  matmul64<CIN0>(actA, wbuf, b0, outB, t);
  __syncthreads();
  stats64(outB, psum, psq, bs, 0, t);
}

__global__ __launch_bounds__(256) void passB_kernel(
    const float* __restrict__ xyz, const float* __restrict__ points,
    const float* __restrict__ newxyz, const int* __restrict__ knn_idx,
    const float* __restrict__ w0, const float* __restrict__ b0,
    const float* __restrict__ w1, const float* __restrict__ b1,
    const float* __restrict__ scales, const float* __restrict__ shifts,
    float* __restrict__ psum, float* __restrict__ psq) {
  __shared__ float actA[K_ * AST];
  __shared__ float outB[K_ * AST];
  __shared__ float wbuf[CIN0 * 64];
  const int bs = blockIdx.x, t = threadIdx.x;
  build_x0(actA, xyz, points, knn_idx, newxyz, bs, t);
  loadw(wbuf, w0, CIN0 * 64, t);
  __syncthreads();
  matmul64<CIN0>(actA, wbuf, b0, outB, t);
  __syncthreads();
  norm_relu64(outB, scales, shifts, t);
  loadw(wbuf, w1, 64 * 64, t);
  __syncthreads();
  matmul64<64>(outB, wbuf, b1, actA, t);
  __syncthreads();
  stats64(actA, psum, psq, bs, 0, t);
}

__global__ __launch_bounds__(256) void passC_kernel(
    const float* __restrict__ xyz, const float* __restrict__ points,
    const float* __restrict__ newxyz, const int* __restrict__ knn_idx,
    const float* __restrict__ w0, const float* __restrict__ b0,
    const float* __restrict__ w1, const float* __restrict__ b1,
    const float* __restrict__ w2, const float* __restrict__ b2,
    const float* __restrict__ scales, const float* __restrict__ shifts,
    float* __restrict__ psum, float* __restrict__ psq,
    float* __restrict__ maxraw, float* __restrict__ minbuf) {
  __shared__ float actA[K_ * AST];
  __shared__ float outB[K_ * AST];
  __shared__ float wbuf[CIN0 * 64];
  const int bs = blockIdx.x, t = threadIdx.x;
  build_x0(actA, xyz, points, knn_idx, newxyz, bs, t);
  loadw(wbuf, w0, CIN0 * 64, t);
  __syncthreads();
  matmul64<CIN0>(actA, wbuf, b0, outB, t);
  __syncthreads();
  norm_relu64(outB, scales, shifts, t);
  loadw(wbuf, w1, 64 * 64, t);
  __syncthreads();
  matmul64<64>(outB, wbuf, b1, actA, t);
  __syncthreads();
  norm_relu64(actA, scales + 128, shifts + 128, t);
  loadw_half(wbuf, w2, 0, t);
  __syncthreads();
  matmul64<64>(actA, wbuf, b2, outB, t);
  __syncthreads();
  stats64(outB, psum, psq, bs, 0, t);
  minmax64(outB, maxraw, minbuf, bs, 0, t);
  loadw_half(wbuf, w2, 64, t);
  __syncthreads();
  matmul64<64>(actA, wbuf, b2 + 64, outB, t);
  __syncthreads();
  stats64(outB, psum, psq, bs, 64, t);
  minmax64(outB, maxraw, minbuf, bs, 64, t);
}

// ---------------- BN finalize ----------------
__global__ __launch_bounds__(256) void finalize_kernel(
    const float* __restrict__ psum, const float* __restrict__ psq,
    const float* __restrict__ g, const float* __restrict__ be,
    float* __restrict__ scale, float* __restrict__ shift) {
  const int ch = blockIdx.x, t = threadIdx.x;
  __shared__ float ss[256];
  __shared__ float sq[256];
  float s = 0.f, q = 0.f;
  for (int p = t; p < NBS; p += 256) {
    s += psum[(size_t)p * 128 + ch];
    q += psq[(size_t)p * 128 + ch];
  }
  ss[t] = s; sq[t] = q;
  __syncthreads();
  for (int off = 128; off >= 1; off >>= 1) {
    if (t < off) { ss[t] += ss[t + off]; sq[t] += sq[t + off]; }
    __syncthreads();
  }
  if (t == 0) {
    const float invN = 1.0f / (float)(B_ * S_ * K_);
    const float mean = ss[0] * invN;
    const float var = sq[0] * invN - mean * mean;
    const float sc = g[ch] / sqrtf(var + 1e-5f);
    scale[ch] = sc;
    shift[ch] = be[ch] - mean * sc;
  }
}

// ---------------- Final ----------------
__global__ __launch_bounds__(256) void final_kernel(
    const float* __restrict__ minbuf, const float* __restrict__ scale,
    const float* __restrict__ shift, float* __restrict__ out) {
  const int i = blockIdx.x * 256 + threadIdx.x;  // < B*S*128
  const int ch = i & 127;
  const float sc = scale[ch], sh = shift[ch];
  const float mx = out[NEWXYZ_FLOATS + i];
  const float mn = minbuf[i];
  const float v = sc * (sc >= 0.f ? mx : mn) + sh;
  out[NEWXYZ_FLOATS + i] = fmaxf(v, 0.f);
}

// ---------------- host ----------------
extern "C" void kernel_launch(void* const* d_in, const int* in_sizes, int n_in,
                              void* d_out, int out_size, void* d_ws, size_t ws_size,
                              hipStream_t stream) {
  const float* xyz = (const float*)d_in[0];
  const float* points = (const float*)d_in[1];
  const float* w0 = (const float*)d_in[2];
  const float* b0 = (const float*)d_in[3];
  const float* g0 = (const float*)d_in[4];
  const float* be0 = (const float*)d_in[5];
  const float* w1 = (const float*)d_in[6];
  const float* b1 = (const float*)d_in[7];
  const float* g1 = (const float*)d_in[8];
  const float* be1 = (const float*)d_in[9];
  const float* w2 = (const float*)d_in[10];
  const float* b2 = (const float*)d_in[11];
  const float* g2 = (const float*)d_in[12];
  const float* be2 = (const float*)d_in[13];
  float* out = (float*)d_out;
  float* newxyz = out;
  float* maxraw = out + NEWXYZ_FLOATS;

  float* ws = (float*)d_ws;
  const size_t NEED_FAST =
      (size_t)(524288 + 16384 * 2048 + 2 * NBS * 128 + 768 + NBS * 128) * 4;

  fps_kernel<<<B_, 256, 0, stream>>>(xyz, newxyz);

  if (ws_size >= NEED_FAST) {
    int* knn_idx = (int*)ws;
    float* zbuf = ws + 524288;
    float* psum = zbuf + (size_t)16384 * 2048;
    float* psq = psum + (size_t)NBS * 128;
    float* scales = psq + (size_t)NBS * 128;
    float* shifts = scales + 384;
    float* minbuf = shifts + 384;
    knn_kernel<<<NBS / 4, 256, 0, stream>>>(xyz, newxyz, knn_idx);
    passA_store_kernel<<<NBS, 256, 0, stream>>>(xyz, points, newxyz, knn_idx, w0, b0,
                                                psum, psq, zbuf);
    finalize_kernel<<<64, 256, 0, stream>>>(psum, psq, g0, be0, scales, shifts);
    passB_z_kernel<<<NBS, 256, 0, stream>>>(w1, b1, scales, shifts, psum, psq, zbuf);
    finalize_kernel<<<64, 256, 0, stream>>>(psum, psq, g1, be1, scales + 128, shifts + 128);
    passC_z_kernel<<<NBS, 256, 0, stream>>>(w2, b2, scales + 128, shifts + 128,
                                            psum, psq, maxraw, minbuf, zbuf);
    finalize_kernel<<<128, 256, 0, stream>>>(psum, psq, g2, be2, scales + 256, shifts + 256);
    final_kernel<<<(B_ * S_ * 128) / 256, 256, 0, stream>>>(minbuf, scales + 256,
                                                            shifts + 256, out);
  } else {
    int* knn_idx = (int*)ws;
    float* psum = ws + 524288;
    float* psq = psum + (size_t)NBS * 128;
    float* scales = psq + (size_t)NBS * 128;
    float* shifts = scales + 384;
    float* minbuf = shifts + 384;
    knn_kernel<<<NBS / 4, 256, 0, stream>>>(xyz, newxyz, knn_idx);
    passA_kernel<<<NBS, 256, 0, stream>>>(xyz, points, newxyz, knn_idx, w0, b0, psum, psq);
    finalize_kernel<<<64, 256, 0, stream>>>(psum, psq, g0, be0, scales, shifts);
    passB_kernel<<<NBS, 256, 0, stream>>>(xyz, points, newxyz, knn_idx, w0, b0, w1, b1,
                                          scales, shifts, psum, psq);
    finalize_kernel<<<64, 256, 0, stream>>>(psum, psq, g1, be1, scales + 128, shifts + 128);
    passC_kernel<<<NBS, 256, 0, stream>>>(xyz, points, newxyz, knn_idx, w0, b0, w1, b1, w2, b2,
                                          scales, shifts, psum, psq, maxraw, minbuf);
    finalize_kernel<<<128, 256, 0, stream>>>(psum, psq, g2, be2, scales + 256, shifts + 256);
    final_kernel<<<(B_ * S_ * 128) / 256, 256, 0, stream>>>(minbuf, scales + 256,
                                                            shifts + 256, out);
  }
}

// Round 7
// 2072.492 us; speedup vs baseline: 1.3794x; 1.0468x over previous
//
#include <hip/hip_runtime.h>
#include <float.h>
#include <math.h>

// Problem constants
#define B_ 16
#define N_ 4096
#define S_ 1024
#define K_ 32
#define CIN0 67              // 3 + 64
#define NBS (B_ * S_)        // 16384
#define NEWXYZ_FLOATS (B_ * S_ * 3)  // 49152
#define AST 68               // LDS activation row stride

// ---------------- helpers ----------------

__device__ __forceinline__ float sqdist3(float x, float y, float z,
                                         float cx, float cy, float cz) {
#pragma clang fp contract(off)
  float dx = x - cx, dy = y - cy, dz = z - cz;
  float s = dx * dx;
  s = s + dy * dy;
  s = s + dz * dz;
  return s;
}

__device__ __forceinline__ float knn_dist(float c2, float cx, float cy, float cz,
                                          float x, float y, float z) {
#pragma clang fp contract(off)
  float dot = cx * x; dot = dot + cy * y; dot = dot + cz * z;
  float x2 = x * x;   x2 = x2 + y * y;   x2 = x2 + z * z;
  float d = c2 - 2.0f * dot;
  d = d + x2;
  return d;
}

// ---- DPP cross-lane (gfx9: row_shr:N=0x110|N, row_bcast15=0x142, row_bcast31=0x143) ----
template <int CTRL>
__device__ __forceinline__ float dpp_f(float v, float oldv) {
  return __int_as_float(__builtin_amdgcn_update_dpp(
      __float_as_int(oldv), __float_as_int(v), CTRL, 0xF, 0xF, false));
}
template <int CTRL>
__device__ __forceinline__ int dpp_i(int v, int oldv) {
  return __builtin_amdgcn_update_dpp(oldv, v, CTRL, 0xF, 0xF, false);
}

// argmax combine on (val,idx); invalid lanes see val=-1 (< any dist>=0)
template <int CTRL>
__device__ __forceinline__ void fps_combine2(float& val, int& idx) {
  const float tv = dpp_f<CTRL>(val, -1.0f);
  const int ti = dpp_i<CTRL>(idx, 0x7fffffff);
  const bool take = (tv > val) || (tv == val && ti < idx);
  val = take ? tv : val;
  idx = take ? ti : idx;
}

// ---------------- FPS: one block (256 thr = 4 waves) per batch ----------------
// Rounds 2-6 lesson: per-step cost was ~2900cyc in EVERY data-path variant
// because the 16 coord loads were threaded through the serial argmax chain
// (compiler groups them inside the dependent chain -> ~5x exposed latency).
// Fix: TWO-PHASE step. Phase L computes dd[16] with NO cross-j dependency
// (16 independent ds_read_b128 batch-issued, FMAs pipeline). sched_barrier
// fences the phases. Phase A is a register-only min/argmax chain. Then DPP
// wave reduce (val,idx), one barrier, float2 candidate resolve, one
// broadcast sp[bj] fetch.
// Bit-exact vs numpy: contract(off) distances, same op order, first-index
// argmax tie-break (ascending index scan; min-idx combine).
__global__ __launch_bounds__(256, 1) void fps_kernel(
    const float* __restrict__ xyz, float* __restrict__ newxyz) {
  const int b = blockIdx.x;
  const int t = threadIdx.x;
  __shared__ float4 sp[N_];      // 64 KB coords (x,y,z,0)
  __shared__ float2 rec[2][4];   // [parity][wave] = (val, idxbits)
  const float* xb = xyz + (size_t)b * N_ * 3;
  for (int p = t; p < N_; p += 256) {
    sp[p] = make_float4(xb[p * 3 + 0], xb[p * 3 + 1], xb[p * 3 + 2], 0.0f);
  }
  float dist[16];
#pragma unroll
  for (int j = 0; j < 16; ++j) dist[j] = 1e10f;
  __syncthreads();
  // first centroid = point 0 (reference: farthest init = 0)
  float4 c0 = sp[0];
  float cx = c0.x, cy = c0.y, cz = c0.z;
  for (int s = 0; s < S_; ++s) {
    if (t == 0) {
      float* o = newxyz + ((size_t)b * S_ + s) * 3;
      o[0] = cx; o[1] = cy; o[2] = cz;
    }
    // ---- Phase L: independent loads + distance computes (no serial chain) ----
    float dd[16];
#pragma unroll
    for (int j = 0; j < 16; ++j) {
      const float4 p = sp[j * 256 + t];
      dd[j] = sqdist3(p.x, p.y, p.z, cx, cy, cz);
    }
    __builtin_amdgcn_sched_barrier(0);  // keep loads out of the argmax chain
    // ---- Phase A: register-only min + local argmax (ascending j -> first on tie) ----
    float best = -1.0f;
    int bi = 0;
#pragma unroll
    for (int j = 0; j < 16; ++j) {
      const float nd = fminf(dist[j], dd[j]);
      dist[j] = nd;
      const bool take = nd > best;
      best = take ? nd : best;
      bi = take ? (j * 256 + t) : bi;
    }
    // DPP wave argmax (result complete in lane 63)
    fps_combine2<0x111>(best, bi);  // row_shr:1
    fps_combine2<0x112>(best, bi);  // row_shr:2
    fps_combine2<0x114>(best, bi);  // row_shr:4
    fps_combine2<0x118>(best, bi);  // row_shr:8
    fps_combine2<0x142>(best, bi);  // row_bcast:15
    fps_combine2<0x143>(best, bi);  // row_bcast:31
    const float wv = __int_as_float(__builtin_amdgcn_readlane(__float_as_int(best), 63));
    const int wi = __builtin_amdgcn_readlane(bi, 63);
    const int par = s & 1;
    if ((t & 63) == 0) {
      rec[par][t >> 6] = make_float2(wv, __int_as_float(wi));
    }
    __syncthreads();
    // all threads resolve the 4 wave candidates redundantly (broadcast b64 reads)
    float2 r0 = rec[par][0];
    float bv = r0.x;
    int bj = __float_as_int(r0.y);
#pragma unroll
    for (int w = 1; w < 4; ++w) {
      const float2 r = rec[par][w];
      const int iw = __float_as_int(r.y);
      const bool take = (r.x > bv) || (r.x == bv && iw < bj);
      bv = take ? r.x : bv;
      bj = take ? iw : bj;
    }
    const float4 c = sp[bj];  // broadcast read
    cx = c.x; cy = c.y; cz = c.z;
  }
}

// ---------------- KNN: one wave per query, 4 queries/block ----------------
__global__ __launch_bounds__(256, 2) void knn_kernel(
    const float* __restrict__ xyz, const float* __restrict__ newxyz,
    int* __restrict__ knn_idx) {
  const int bs0 = blockIdx.x * 4;
  const int b = bs0 >> 10;
  const int t = threadIdx.x;
  const int wave = t >> 6;
  const int lane = t & 63;
  __shared__ float sxx[N_];
  __shared__ float sxy[N_];
  __shared__ float sxz[N_];
  const float* xb = xyz + (size_t)b * N_ * 3;
  for (int p = t; p < N_; p += 256) {
    sxx[p] = xb[p * 3 + 0];
    sxy[p] = xb[p * 3 + 1];
    sxz[p] = xb[p * 3 + 2];
  }
  __syncthreads();
  const int bs = bs0 + wave;
  const float cx = newxyz[(size_t)bs * 3 + 0];
  const float cy = newxyz[(size_t)bs * 3 + 1];
  const float cz = newxyz[(size_t)bs * 3 + 2];
  float c2;
  {
#pragma clang fp contract(off)
    float s = cx * cx;
    s = s + cy * cy;
    s = s + cz * cz;
    c2 = s;
  }
  float d[64];
  float gval[8];
  int gidx[8];
#pragma unroll
  for (int g = 0; g < 8; ++g) {
    float gv = FLT_MAX;
    int gi = g * 8;
#pragma unroll
    for (int q = 0; q < 8; ++q) {
      const int j = g * 8 + q;
      const int p = j * 64 + lane;
      const float dd = knn_dist(c2, cx, cy, cz, sxx[p], sxy[p], sxz[p]);
      d[j] = dd;
      if (dd < gv) { gv = dd; gi = j; }
    }
    gval[g] = gv; gidx[g] = gi;
  }
  int* krow = knn_idx + (size_t)bs * K_;
  for (int it = 0; it < K_; ++it) {
    float best = gval[0];
    int bj = gidx[0];
#pragma unroll
    for (int g = 1; g < 8; ++g) {
      if (gval[g] < best || (gval[g] == best && gidx[g] < bj)) { best = gval[g]; bj = gidx[g]; }
    }
    int bidx = bj * 64 + lane;
#pragma unroll
    for (int off = 32; off >= 1; off >>= 1) {
      const float ov = __shfl_xor(best, off);
      const int oi = __shfl_xor(bidx, off);
      if (ov < best || (ov == best && oi < bidx)) { best = ov; bidx = oi; }
    }
    if (lane == 0) krow[it] = bidx;
    if (lane == (bidx & 63)) {
      const int jl = bidx >> 6;
      const int gg = jl >> 3;
      const int qq = jl & 7;
#pragma unroll
      for (int g = 0; g < 8; ++g) {
        if (g == gg) {
#pragma unroll
          for (int q = 0; q < 8; ++q) {
            d[g * 8 + q] = (q == qq) ? FLT_MAX : d[g * 8 + q];
          }
          float gv = FLT_MAX;
          int gi = g * 8;
#pragma unroll
          for (int q = 0; q < 8; ++q) {
            const int j = g * 8 + q;
            if (d[j] < gv) { gv = d[j]; gi = j; }
          }
          gval[g] = gv; gidx[g] = gi;
        }
      }
    }
  }
}

// ---------------- MLP pass building blocks ----------------

__device__ __forceinline__ void loadw(float* __restrict__ wbuf,
                                      const float* __restrict__ w, int n, int t) {
  for (int i = t; i < n; i += 256) wbuf[i] = w[i];
}

__device__ __forceinline__ void loadw_half(float* __restrict__ wbuf,
                                           const float* __restrict__ w2, int ofs, int t) {
  for (int i = t; i < 64 * 64; i += 256) {
    const int c = i >> 6, j = i & 63;
    wbuf[i] = w2[c * 128 + ofs + j];
  }
}

__device__ __forceinline__ void build_x0(float* __restrict__ act,
    const float* __restrict__ xyz, const float* __restrict__ points,
    const int* __restrict__ knn_idx, const float* __restrict__ newxyz,
    int bs, int t) {
  const int b = bs >> 10;
  const int* krow = knn_idx + (size_t)bs * K_;
  const float cx = newxyz[(size_t)bs * 3 + 0];
  const float cy = newxyz[(size_t)bs * 3 + 1];
  const float cz = newxyz[(size_t)bs * 3 + 2];
  for (int i = t; i < K_ * CIN0; i += 256) {
    const int k = i / CIN0;
    const int c = i - k * CIN0;
    const int p = krow[k];
    float v;
    if (c < 3) {
      v = xyz[((size_t)b * N_ + p) * 3 + c] - (c == 0 ? cx : (c == 1 ? cy : cz));
    } else {
      v = points[((size_t)b * N_ + p) * 64 + (c - 3)];
    }
    act[k * AST + c] = v;
  }
}

template <int CIN>
__device__ __forceinline__ void matmul64(const float* __restrict__ act,
    const float* __restrict__ wbuf, const float* __restrict__ bias,
    float* __restrict__ out, int t) {
  const int k = t >> 3;
  const int g = t & 7;
  float acc[8];
#pragma unroll
  for (int j = 0; j < 8; ++j) acc[j] = bias[g * 8 + j];
  for (int c = 0; c < CIN; ++c) {
    const float xv = act[k * AST + c];
#pragma unroll
    for (int j = 0; j < 8; ++j) acc[j] += xv * wbuf[c * 64 + g * 8 + j];
  }
#pragma unroll
  for (int j = 0; j < 8; ++j) out[k * AST + g * 8 + j] = acc[j];
}

__device__ __forceinline__ void norm_relu64(float* __restrict__ act,
    const float* __restrict__ scale, const float* __restrict__ shift, int t) {
  for (int i = t; i < K_ * 64; i += 256) {
    const int k = i >> 6, c = i & 63;
    const float v = act[k * AST + c] * scale[c] + shift[c];
    act[k * AST + c] = fmaxf(v, 0.0f);
  }
}

__device__ __forceinline__ void stats64(const float* __restrict__ out,
    float* __restrict__ psum, float* __restrict__ psq, int bs, int ofs, int t) {
  if (t < 64) {
    float s = 0.f, q = 0.f;
    for (int k = 0; k < K_; ++k) {
      const float v = out[k * AST + t];
      s += v; q += v * v;
    }
    psum[(size_t)bs * 128 + ofs + t] = s;
    psq[(size_t)bs * 128 + ofs + t] = q;
  }
}

__device__ __forceinline__ void minmax64(const float* __restrict__ out,
    float* __restrict__ maxraw, float* __restrict__ minbuf, int bs, int ofs, int t) {
  if (t >= 64 && t < 128) {
    const int ch = t - 64;
    float mx = -FLT_MAX, mn = FLT_MAX;
    for (int k = 0; k < K_; ++k) {
      const float v = out[k * AST + ch];
      mx = fmaxf(mx, v); mn = fminf(mn, v);
    }
    maxraw[(size_t)bs * 128 + ofs + ch] = mx;
    minbuf[(size_t)bs * 128 + ofs + ch] = mn;
  }
}

// ======== FAST PATH (activations stored in ws) ========

__global__ __launch_bounds__(256) void passA_store_kernel(
    const float* __restrict__ xyz, const float* __restrict__ points,
    const float* __restrict__ newxyz, const int* __restrict__ knn_idx,
    const float* __restrict__ w0, const float* __restrict__ b0,
    float* __restrict__ psum, float* __restrict__ psq, float* __restrict__ zbuf) {
  __shared__ float actA[K_ * AST];
  __shared__ float outB[K_ * AST];
  __shared__ float wbuf[CIN0 * 64];
  const int bs = blockIdx.x, t = threadIdx.x;
  build_x0(actA, xyz, points, knn_idx, newxyz, bs, t);
  loadw(wbuf, w0, CIN0 * 64, t);
  __syncthreads();
  matmul64<CIN0>(actA, wbuf, b0, outB, t);
  __syncthreads();
  stats64(outB, psum, psq, bs, 0, t);
  float* zrow = zbuf + (size_t)bs * 2048;
  for (int i = t; i < 2048; i += 256) zrow[i] = outB[(i >> 6) * AST + (i & 63)];
}

__global__ __launch_bounds__(256) void passB_z_kernel(
    const float* __restrict__ w1, const float* __restrict__ b1,
    const float* __restrict__ scales, const float* __restrict__ shifts,
    float* __restrict__ psum, float* __restrict__ psq, float* __restrict__ zbuf) {
  __shared__ float actA[K_ * AST];
  __shared__ float outB[K_ * AST];
  __shared__ float wbuf[64 * 64];
  const int bs = blockIdx.x, t = threadIdx.x;
  float* zrow = zbuf + (size_t)bs * 2048;
  for (int i = t; i < 2048; i += 256) outB[(i >> 6) * AST + (i & 63)] = zrow[i];
  loadw(wbuf, w1, 64 * 64, t);
  __syncthreads();
  norm_relu64(outB, scales, shifts, t);
  __syncthreads();
  matmul64<64>(outB, wbuf, b1, actA, t);
  __syncthreads();
  stats64(actA, psum, psq, bs, 0, t);
  for (int i = t; i < 2048; i += 256) zrow[i] = actA[(i >> 6) * AST + (i & 63)];
}

__global__ __launch_bounds__(256) void passC_z_kernel(
    const float* __restrict__ w2, const float* __restrict__ b2,
    const float* __restrict__ scales1, const float* __restrict__ shifts1,
    float* __restrict__ psum, float* __restrict__ psq,
    float* __restrict__ maxraw, float* __restrict__ minbuf,
    const float* __restrict__ zbuf) {
  __shared__ float actA[K_ * AST];
  __shared__ float outB[K_ * AST];
  __shared__ float wbuf[64 * 64];
  const int bs = blockIdx.x, t = threadIdx.x;
  const float* zrow = zbuf + (size_t)bs * 2048;
  for (int i = t; i < 2048; i += 256) actA[(i >> 6) * AST + (i & 63)] = zrow[i];
  loadw_half(wbuf, w2, 0, t);
  __syncthreads();
  norm_relu64(actA, scales1, shifts1, t);
  __syncthreads();
  matmul64<64>(actA, wbuf, b2, outB, t);
  __syncthreads();
  stats64(outB, psum, psq, bs, 0, t);
  minmax64(outB, maxraw, minbuf, bs, 0, t);
  loadw_half(wbuf, w2, 64, t);
  __syncthreads();
  matmul64<64>(actA, wbuf, b2 + 64, outB, t);
  __syncthreads();
  stats64(outB, psum, psq, bs, 64, t);
  minmax64(outB, maxraw, minbuf, bs, 64, t);
}

// ======== FALLBACK PATH (recompute) ========

__global__ __launch_bounds__(256) void passA_kernel(
    const float* __restrict__ xyz, const float* __restrict__ points,
    const float* __restrict__ newxyz, const int* __restrict__ knn_idx,
    const float* __restrict__ w0, const float* __restrict__ b0,
    float* __restrict__ psum, float* __restrict__ psq) {
  __shared__ float actA[K_ * AST];
  __shared__ float outB[K_ * AST];
  __shared__ float wbuf[CIN0 * 64];
  const int bs = blockIdx.x, t = threadIdx.x;
  build_x0(actA, xyz, points, knn_idx, newxyz, bs, t);
  loadw(wbuf, w0, CIN0 * 64, t);
  __syncthreads();
  matmul64<CIN0>(actA, wbuf, b0, outB, t);
  __syncthreads();
  stats64(outB, psum, psq, bs, 0, t);
}

__global__ __launch_bounds__(256) void passB_kernel(
    const float* __restrict__ xyz, const float* __restrict__ points,
    const float* __restrict__ newxyz, const int* __restrict__ knn_idx,
    const float* __restrict__ w0, const float* __restrict__ b0,
    const float* __restrict__ w1, const float* __restrict__ b1,
    const float* __restrict__ scales, const float* __restrict__ shifts,
    float* __restrict__ psum, float* __restrict__ psq) {
  __shared__ float actA[K_ * AST];
  __shared__ float outB[K_ * AST];
  __shared__ float wbuf[CIN0 * 64];
  const int bs = blockIdx.x, t = threadIdx.x;
  build_x0(actA, xyz, points, knn_idx, newxyz, bs, t);
  loadw(wbuf, w0, CIN0 * 64, t);
  __syncthreads();
  matmul64<CIN0>(actA, wbuf, b0, outB, t);
  __syncthreads();
  norm_relu64(outB, scales, shifts, t);
  loadw(wbuf, w1, 64 * 64, t);
  __syncthreads();
  matmul64<64>(outB, wbuf, b1, actA, t);
  __syncthreads();
  stats64(actA, psum, psq, bs, 0, t);
}

__global__ __launch_bounds__(256) void passC_kernel(
    const float* __restrict__ xyz, const float* __restrict__ points,
    const float* __restrict__ newxyz, const int* __restrict__ knn_idx,
    const float* __restrict__ w0, const float* __restrict__ b0,
    const float* __restrict__ w1, const float* __restrict__ b1,
    const float* __restrict__ w2, const float* __restrict__ b2,
    const float* __restrict__ scales, const float* __restrict__ shifts,
    float* __restrict__ psum, float* __restrict__ psq,
    float* __restrict__ maxraw, float* __restrict__ minbuf) {
  __shared__ float actA[K_ * AST];
  __shared__ float outB[K_ * AST];
  __shared__ float wbuf[CIN0 * 64];
  const int bs = blockIdx.x, t = threadIdx.x;
  build_x0(actA, xyz, points, knn_idx, newxyz, bs, t);
  loadw(wbuf, w0, CIN0 * 64, t);
  __syncthreads();
  matmul64<CIN0>(actA, wbuf, b0, outB, t);
  __syncthreads();
  norm_relu64(outB, scales, shifts, t);
  loadw(wbuf, w1, 64 * 64, t);
  __syncthreads();
  matmul64<64>(outB, wbuf, b1, actA, t);
  __syncthreads();
  norm_relu64(actA, scales + 128, shifts + 128, t);
  loadw_half(wbuf, w2, 0, t);
  __syncthreads();
  matmul64<64>(actA, wbuf, b2, outB, t);
  __syncthreads();
  stats64(outB, psum, psq, bs, 0, t);
  minmax64(outB, maxraw, minbuf, bs, 0, t);
  loadw_half(wbuf, w2, 64, t);
  __syncthreads();
  matmul64<64>(actA, wbuf, b2 + 64, outB, t);
  __syncthreads();
  stats64(outB, psum, psq, bs, 64, t);
  minmax64(outB, maxraw, minbuf, bs, 64, t);
}

// ---------------- BN finalize ----------------
__global__ __launch_bounds__(256) void finalize_kernel(
    const float* __restrict__ psum, const float* __restrict__ psq,
    const float* __restrict__ g, const float* __restrict__ be,
    float* __restrict__ scale, float* __restrict__ shift) {
  const int ch = blockIdx.x, t = threadIdx.x;
  __shared__ float ss[256];
  __shared__ float sq[256];
  float s = 0.f, q = 0.f;
  for (int p = t; p < NBS; p += 256) {
    s += psum[(size_t)p * 128 + ch];
    q += psq[(size_t)p * 128 + ch];
  }
  ss[t] = s; sq[t] = q;
  __syncthreads();
  for (int off = 128; off >= 1; off >>= 1) {
    if (t < off) { ss[t] += ss[t + off]; sq[t] += sq[t + off]; }
    __syncthreads();
  }
  if (t == 0) {
    const float invN = 1.0f / (float)(B_ * S_ * K_);
    const float mean = ss[0] * invN;
    const float var = sq[0] * invN - mean * mean;
    const float sc = g[ch] / sqrtf(var + 1e-5f);
    scale[ch] = sc;
    shift[ch] = be[ch] - mean * sc;
  }
}

// ---------------- Final ----------------
__global__ __launch_bounds__(256) void final_kernel(
    const float* __restrict__ minbuf, const float* __restrict__ scale,
    const float* __restrict__ shift, float* __restrict__ out) {
  const int i = blockIdx.x * 256 + threadIdx.x;  // < B*S*128
  const int ch = i & 127;
  const float sc = scale[ch], sh = shift[ch];
  const float mx = out[NEWXYZ_FLOATS + i];
  const float mn = minbuf[i];
  const float v = sc * (sc >= 0.f ? mx : mn) + sh;
  out[NEWXYZ_FLOATS + i] = fmaxf(v, 0.f);
}

// ---------------- host ----------------
extern "C" void kernel_launch(void* const* d_in, const int* in_sizes, int n_in,
                              void* d_out, int out_size, void* d_ws, size_t ws_size,
                              hipStream_t stream) {
  const float* xyz = (const float*)d_in[0];
  const float* points = (const float*)d_in[1];
  const float* w0 = (const float*)d_in[2];
  const float* b0 = (const float*)d_in[3];
  const float* g0 = (const float*)d_in[4];
  const float* be0 = (const float*)d_in[5];
  const float* w1 = (const float*)d_in[6];
  const float* b1 = (const float*)d_in[7];
  const float* g1 = (const float*)d_in[8];
  const float* be1 = (const float*)d_in[9];
  const float* w2 = (const float*)d_in[10];
  const float* b2 = (const float*)d_in[11];
  const float* g2 = (const float*)d_in[12];
  const float* be2 = (const float*)d_in[13];
  float* out = (float*)d_out;
  float* newxyz = out;
  float* maxraw = out + NEWXYZ_FLOATS;

  float* ws = (float*)d_ws;
  const size_t NEED_FAST =
      (size_t)(524288 + 16384 * 2048 + 2 * NBS * 128 + 768 + NBS * 128) * 4;

  fps_kernel<<<B_, 256, 0, stream>>>(xyz, newxyz);

  if (ws_size >= NEED_FAST) {
    int* knn_idx = (int*)ws;
    float* zbuf = ws + 524288;
    float* psum = zbuf + (size_t)16384 * 2048;
    float* psq = psum + (size_t)NBS * 128;
    float* scales = psq + (size_t)NBS * 128;
    float* shifts = scales + 384;
    float* minbuf = shifts + 384;
    knn_kernel<<<NBS / 4, 256, 0, stream>>>(xyz, newxyz, knn_idx);
    passA_store_kernel<<<NBS, 256, 0, stream>>>(xyz, points, newxyz, knn_idx, w0, b0,
                                                psum, psq, zbuf);
    finalize_kernel<<<64, 256, 0, stream>>>(psum, psq, g0, be0, scales, shifts);
    passB_z_kernel<<<NBS, 256, 0, stream>>>(w1, b1, scales, shifts, psum, psq, zbuf);
    finalize_kernel<<<64, 256, 0, stream>>>(psum, psq, g1, be1, scales + 128, shifts + 128);
    passC_z_kernel<<<NBS, 256, 0, stream>>>(w2, b2, scales + 128, shifts + 128,
                                            psum, psq, maxraw, minbuf, zbuf);
    finalize_kernel<<<128, 256, 0, stream>>>(psum, psq, g2, be2, scales + 256, shifts + 256);
    final_kernel<<<(B_ * S_ * 128) / 256, 256, 0, stream>>>(minbuf, scales + 256,
                                                            shifts + 256, out);
  } else {
    int* knn_idx = (int*)ws;
    float* psum = ws + 524288;
    float* psq = psum + (size_t)NBS * 128;
    float* scales = psq + (size_t)NBS * 128;
    float* shifts = scales + 384;
    float* minbuf = shifts + 384;
    knn_kernel<<<NBS / 4, 256, 0, stream>>>(xyz, newxyz, knn_idx);
    passA_kernel<<<NBS, 256, 0, stream>>>(xyz, points, newxyz, knn_idx, w0, b0, psum, psq);
    finalize_kernel<<<64, 256, 0, stream>>>(psum, psq, g0, be0, scales, shifts);
    passB_kernel<<<NBS, 256, 0, stream>>>(xyz, points, newxyz, knn_idx, w0, b0, w1, b1,
                                          scales, shifts, psum, psq);
    finalize_kernel<<<64, 256, 0, stream>>>(psum, psq, g1, be1, scales + 128, shifts + 128);
    passC_kernel<<<NBS, 256, 0, stream>>>(xyz, points, newxyz, knn_idx, w0, b0, w1, b1, w2, b2,
                                          scales, shifts, psum, psq, maxraw, minbuf);
    finalize_kernel<<<128, 256, 0, stream>>>(psum, psq, g2, be2, scales + 256, shifts + 256);
    final_kernel<<<(B_ * S_ * 128) / 256, 256, 0, stream>>>(minbuf, scales + 256,
                                                            shifts + 256, out);
  }
}